// Round 7
// baseline (2459.211 us; speedup 1.0000x reference)
//
#include <hip/hip_runtime.h>
#include <math.h>

#define KCH 128
#define NELEM 10
#define NPAIR 136   // 16*17/2
#define PSZ   2176  // NPAIR*16

__device__ __forceinline__ int lidxf(int m){ return (m==0)?0:((m<4)?1:((m<9)?2:3)); }
__device__ __forceinline__ float siluf(float z){ return z/(1.f+expf(-z)); }
__device__ __forceinline__ float dsiluf(float z){ float s=1.f/(1.f+expf(-z)); return s*(1.f+z*(1.f-s)); }

// ---------------- utility ----------------
__global__ void k_zero(float* p, int n){
  int i = blockIdx.x*256 + threadIdx.x;
  if(i<n) p[i]=0.f;
}

__global__ void k_elem(const float* attrs, int* elem, int N){
  int n = blockIdx.x*256 + threadIdx.x;
  if(n>=N) return;
  int z=0;
  for(int e=0;e<NELEM;++e) if(attrs[n*NELEM+e] > 0.5f) z=e;
  elem[n]=z;
}

__global__ void k_h0(const float* Wemb, const int* elem, float* h0, int N){
  int i = blockIdx.x*256 + threadIdx.x;
  if(i>=N*KCH) return;
  int n = i>>7, k = i&127;
  h0[i] = Wemb[elem[n]*KCH + k];
}

__global__ void k_hist(const int* keys, int* cnt, int n){
  int i = blockIdx.x*256 + threadIdx.x;
  if(i<n) atomicAdd(&cnt[keys[i]],1);
}

__global__ void k_scan(const int* cnt, int* ptr, int n){
  __shared__ int part[257];
  int t = threadIdx.x;
  int csz = (n+255)/256;
  int lo = t*csz, hi = (t+1)*csz; if(hi>n) hi=n;
  int s=0;
  for(int i=lo;i<hi;++i) s+=cnt[i];
  part[t]=s; __syncthreads();
  if(t==0){ int acc=0; for(int i=0;i<256;++i){ int v=part[i]; part[i]=acc; acc+=v; } part[256]=acc; }
  __syncthreads();
  int acc = part[t];
  for(int i=lo;i<hi;++i){ ptr[i]=acc; acc+=cnt[i]; }
  if(t==255) ptr[n]=part[256];
}

__global__ void k_scatter(const int* keys, const int* ptr, int* cur, int* idx, int n){
  int i = blockIdx.x*256 + threadIdx.x;
  if(i>=n) return;
  int k = keys[i];
  int p = atomicAdd(&cur[k],1);
  idx[ptr[k]+p] = i;
}

// ---------------- fused weight prep ----------------
__global__ void k_prep(const float* Wup, const float* Wprod, const float* Wskip, const float* Wlin,
                       const float* Wr2, const float* Wr3, const float* U2, const float* U3,
                       float* WupT1, float* WprodT0, float* WskipT1,
                       float* Wbig0, float* Wbig1, float* WbigT0, float* WbigT1,
                       float* Wr3T0, float* Wr3T1, float* Wr2T0, float* Wr2T1,
                       float* U2s, float* U3s){
  int i = blockIdx.x*256 + threadIdx.x;
  const int KK = 16384;
  if(i < KK){ int r=i>>7, c=i&127; WupT1[c*128+r] = Wup[KK + i]; return; }
  i -= KK;
  if(i < KK){ int r=i>>7, c=i&127; WprodT0[c*128+r] = Wprod[i]; return; }
  i -= KK;
  if(i < NELEM*KK){ int mat=i>>14, rc=i&16383, r=rc>>7, c=rc&127;
    WskipT1[mat*KK + c*128 + r] = Wskip[(size_t)NELEM*KK + i]; return; }
  i -= NELEM*KK;
  if(i < 16*KK){ int m=i>>14, sk=i&16383; Wbig0[i] = Wlin[lidxf(m)*KK + sk]; return; }
  i -= 16*KK;
  if(i < 16*KK){ int m=i>>14, sk=i&16383; Wbig1[i] = Wlin[4*KK + lidxf(m)*KK + sk]; return; }
  i -= 16*KK;
  if(i < 16*KK){ int m=i>>14, sk=i&16383, s=sk>>7, k=sk&127; WbigT0[i] = Wlin[lidxf(m)*KK + k*128 + s]; return; }
  i -= 16*KK;
  if(i < 16*KK){ int m=i>>14, sk=i&16383, s=sk>>7, k=sk&127; WbigT1[i] = Wlin[4*KK + lidxf(m)*KK + k*128 + s]; return; }
  i -= 16*KK;
  if(i < 32768){ int r=i>>9, c=i&511; Wr3T0[c*64+r] = Wr3[i]; return; }
  i -= 32768;
  if(i < 32768){ int r=i>>9, c=i&511; Wr3T1[c*64+r] = Wr3[32768 + i]; return; }
  i -= 32768;
  if(i < 4096){ int r=i>>6, c=i&63; Wr2T0[c*64+r] = Wr2[i]; return; }
  i -= 4096;
  if(i < 4096){ int r=i>>6, c=i&63; Wr2T1[c*64+r] = Wr2[4096 + i]; return; }
  i -= 4096;
  if(i < 1024){ int p=i&3, b=(i>>2)&15, a=(i>>6)&15;
    U2s[i] = U2[a*64+b*4+p] + U2[b*64+a*4+p]; return; }
  i -= 1024;
  if(i < 32768){
    int p=i&7, c=(i>>3)&15, b=(i>>7)&15, a=(i>>11)&15;
    U3s[i] = U3[a*2048+b*128+c*8+p] + U3[a*2048+c*128+b*8+p]
           + U3[b*2048+a*128+c*8+p] + U3[b*2048+c*128+a*8+p]
           + U3[c*2048+a*128+b*8+p] + U3[c*2048+b*128+a*8+p];
    return;
  }
}
#define PREP_ITEMS (16384*76 + 32768*2 + 4096*2 + 1024 + 32768)

// ---------------- fused contracted tensors (per layer) ----------------
__global__ void k_ctens(const float* U1, const float* U2s, const float* U3s,
                        const float* Wc1l, const float* Wc2l, const float* Wc3l,
                        float* C1, float* C2S, float* P){
  int i = blockIdx.x*256 + threadIdx.x;
  if(i < NELEM*KCH*16){
    int a=i&15, c=(i>>4)&127, z=i>>11;
    float s=0;
    for(int p=0;p<2;++p) s += U1[a*2+p]*Wc1l[z*2*KCH + p*KCH + c];
    C1[i]=s; return;
  }
  i -= NELEM*KCH*16;
  if(i < NELEM*KCH*256){
    int ab=i&255, c=(i>>8)&127, z=i>>15;
    float s=0;
    for(int p=0;p<4;++p) s += U2s[ab*4+p]*Wc2l[z*4*KCH + p*KCH + c];
    C2S[i]=s; return;
  }
  i -= NELEM*KCH*256;
  if(i < NELEM*KCH*PSZ){
    int x = i & 15;
    int t2 = i >> 4;
    int pair = t2 % NPAIR;
    int cz = t2 / NPAIR;
    int c = cz & 127, z = cz >> 7;
    int j=0, rem=pair;
    while(rem >= 16-j){ rem -= 16-j; ++j; }
    int k = j + rem;
    const float* u = U3s + (size_t)j*2048 + k*128 + x*8;
    float s=0;
    #pragma unroll
    for(int p=0;p<8;++p) s += u[p]*Wc3l[z*8*KCH + p*KCH + c];
    if(j==k) s *= 0.5f;
    P[i] = s; return;
  }
}
#define CTENS_ITEMS (NELEM*KCH*16 + NELEM*KCH*256 + NELEM*KCH*PSZ)

__global__ void k_gB1(const float* Wro, const float* Wprod1, float* gB1){
  int c = threadIdx.x;
  float s=0;
  for(int h=0;h<KCH;++h) s += Wro[h]*Wprod1[c*KCH+h];
  gB1[c]=s;
}

// ---------------- edge geometry (writes in recv-sorted order) ----------------
__global__ void k_edge_geom(const float* pos, const float* shifts, const int* ei, const int* ridx, int E,
                            int* snds, int* rcvs,
                            float* vec, float* rr, float* Y, float* dY, float* ef, float* defdr){
  int i = blockIdx.x*256 + threadIdx.x;
  if(i>=E) return;
  int e = ridx[i];
  int s = ei[e], rc = ei[E+e];
  snds[i]=s; rcvs[i]=rc;
  float vx = pos[rc*3+0]-pos[s*3+0]+shifts[e*3+0];
  float vy = pos[rc*3+1]-pos[s*3+1]+shifts[e*3+1];
  float vz = pos[rc*3+2]-pos[s*3+2]+shifts[e*3+2];
  float r2 = vx*vx+vy*vy+vz*vz + 1e-12f;
  float n = sqrtf(r2);
  float inv_n = 1.f/n;
  float x = vx*inv_n, y = vy*inv_n, z = vz*inv_n;
  vec[i*3+0]=vx; vec[i*3+1]=vy; vec[i*3+2]=vz; rr[i]=n;
  const float s3=1.7320508075688772f, s15=3.8729833462074170f, s5=2.2360679774997896f;
  const float s70=8.3666002653407556f, s105=10.2469507659595980f, s42=6.4807406984078604f, s7=2.6457513110645907f;
  float Yv[16], d0[16], d1[16], d2[16];
  Yv[0]=1.f; d0[0]=0;d1[0]=0;d2[0]=0;
  Yv[1]=s3*x; d0[1]=s3; d1[1]=0; d2[1]=0;
  Yv[2]=s3*y; d0[2]=0; d1[2]=s3; d2[2]=0;
  Yv[3]=s3*z; d0[3]=0; d1[3]=0; d2[3]=s3;
  Yv[4]=s15*x*y; d0[4]=s15*y; d1[4]=s15*x; d2[4]=0;
  Yv[5]=s15*y*z; d0[5]=0; d1[5]=s15*z; d2[5]=s15*y;
  Yv[6]=0.5f*s5*(3.f*z*z-1.f); d0[6]=0; d1[6]=0; d2[6]=3.f*s5*z;
  Yv[7]=s15*x*z; d0[7]=s15*z; d1[7]=0; d2[7]=s15*x;
  Yv[8]=0.5f*s15*(x*x-y*y); d0[8]=s15*x; d1[8]=-s15*y; d2[8]=0;
  Yv[9]=0.25f*s70*y*(3.f*x*x-y*y); d0[9]=1.5f*s70*x*y; d1[9]=0.75f*s70*(x*x-y*y); d2[9]=0;
  Yv[10]=s105*x*y*z; d0[10]=s105*y*z; d1[10]=s105*x*z; d2[10]=s105*x*y;
  Yv[11]=0.25f*s42*y*(5.f*z*z-1.f); d0[11]=0; d1[11]=0.25f*s42*(5.f*z*z-1.f); d2[11]=2.5f*s42*y*z;
  Yv[12]=0.5f*s7*z*(5.f*z*z-3.f); d0[12]=0; d1[12]=0; d2[12]=0.5f*s7*(15.f*z*z-3.f);
  Yv[13]=0.25f*s42*x*(5.f*z*z-1.f); d0[13]=0.25f*s42*(5.f*z*z-1.f); d1[13]=0; d2[13]=2.5f*s42*x*z;
  Yv[14]=0.5f*s105*z*(x*x-y*y); d0[14]=s105*x*z; d1[14]=-s105*y*z; d2[14]=0.5f*s105*(x*x-y*y);
  Yv[15]=0.25f*s70*x*(3.f*x*x-y*y); d0[15]=0.25f*s70*(9.f*x*x-y*y); d1[15]=-0.5f*s70*x*y; d2[15]=0;
  #pragma unroll
  for(int m=0;m<16;++m){
    float dm = d0[m]*x + d1[m]*y + d2[m]*z;
    dY[(size_t)i*48 + m*3 + 0] = (d0[m]-dm*x)*inv_n;
    dY[(size_t)i*48 + m*3 + 1] = (d1[m]-dm*y)*inv_n;
    dY[(size_t)i*48 + m*3 + 2] = (d2[m]-dm*z)*inv_n;
    Y[(size_t)i*16+m] = Yv[m];
  }
  const float c0 = 0.63245553203367587f; // sqrt(2/5)
  float rp = n + 1e-9f;
  float u = n*0.2f;
  float f, dfdr;
  if(u < 1.f){
    float u2=u*u, u4=u2*u2, u5=u4*u, u6=u5*u, u7=u6*u;
    f = 1.f - 21.f*u5 + 35.f*u6 - 15.f*u7;
    float dfdu = -105.f*u4 + 210.f*u5 - 105.f*u6;
    dfdr = dfdu*0.2f;
  } else { f=0.f; dfdr=0.f; }
  for(int b=0;b<8;++b){
    float kn = (float)(b+1)*0.62831853071795865f; // pi/5
    float sr = sinf(kn*n), cr = cosf(kn*n);
    float bess = c0*sr/rp;
    float dbess = c0*(kn*cr/rp - sr/(rp*rp));
    ef[(size_t)i*8+b] = bess*f;
    defdr[(size_t)i*8+b] = dbess*f + bess*dfdr;
  }
}

// ---------------- small row-block matmul ----------------
__global__ __launch_bounds__(128) void k_mm(const float* X, const float* W, float* Out, int N, int acc){
  __shared__ float xs[8][KCH];
  int t = threadIdx.x;
  int n0 = blockIdx.x*8;
  for(int j=0;j<8;++j){ int n=n0+j; xs[j][t] = (n<N)? X[(size_t)n*KCH+t] : 0.f; }
  __syncthreads();
  float a[8] = {0,0,0,0,0,0,0,0};
  for(int s=0;s<KCH;++s){
    float wv = W[s*KCH + t];
    #pragma unroll
    for(int j=0;j<8;++j) a[j] += xs[j][s]*wv;
  }
  for(int j=0;j<8;++j){
    int n=n0+j;
    if(n<N){ if(acc) Out[(size_t)n*KCH+t] += a[j]; else Out[(size_t)n*KCH+t] = a[j]; }
  }
}

// ---------------- radial MLP -> w (E x 512, sorted order) ----------------
__global__ __launch_bounds__(256) void k_radial_w(const float* ef, const float* Wr1, const float* Wr2, const float* Wr3,
                                                  float* w, int E){
  __shared__ float t1s[16][64];
  __shared__ float t2s[16][64];
  int t = threadIdx.x;
  int e0 = blockIdx.x*16;
  for(int it=0; it<4; ++it){
    int item = t + it*256;
    int el = item>>6, j = item&63;
    float z=0;
    if(e0+el < E){
      const float* efe = ef + (size_t)(e0+el)*8;
      #pragma unroll
      for(int b=0;b<8;++b) z += efe[b]*Wr1[b*64+j];
    }
    t1s[el][j] = siluf(z);
  }
  __syncthreads();
  for(int it=0; it<4; ++it){
    int item = t + it*256;
    int el = item>>6, j = item&63;
    float z=0;
    #pragma unroll
    for(int i=0;i<64;++i) z += t1s[el][i]*Wr2[i*64+j];
    t2s[el][j] = siluf(z);
  }
  __syncthreads();
  float a0[16], a1[16];
  #pragma unroll
  for(int el=0;el<16;++el){ a0[el]=0.f; a1[el]=0.f; }
  for(int j=0;j<64;++j){
    float wa = Wr3[j*512 + t];
    float wb = Wr3[j*512 + t + 256];
    #pragma unroll
    for(int el=0;el<16;++el){
      float tv = t2s[el][j];
      a0[el] += tv*wa;
      a1[el] += tv*wb;
    }
  }
  for(int el=0;el<16;++el){
    if(e0+el < E){
      w[(size_t)(e0+el)*512 + t] = a0[el];
      w[(size_t)(e0+el)*512 + t + 256] = a1[el];
    }
  }
}

// ---------------- message aggregation ----------------
__global__ __launch_bounds__(256) void k_gather(const float* hup, const float* w, const float* Y,
                                                const int* rptr, const int* snds,
                                                float* agg, int E){
  int n = blockIdx.x;
  int t = threadIdx.x;
  int k = t & 127, mg = t >> 7;
  float acc[8] = {0,0,0,0,0,0,0,0};
  int s0 = rptr[n], s1 = rptr[n+1];
  for(int i=s0;i<s1;++i){
    int snd = snds[i];
    float hv = hup[(size_t)snd*KCH + k];
    float4 w4 = ((const float4*)(w + (size_t)i*512))[k];
    const float* Ye = Y + (size_t)i*16 + mg*8;
    if(mg==0){
      acc[0] += w4.x*hv*Ye[0];
      acc[1] += w4.y*hv*Ye[1];
      acc[2] += w4.y*hv*Ye[2];
      acc[3] += w4.y*hv*Ye[3];
      acc[4] += w4.z*hv*Ye[4];
      acc[5] += w4.z*hv*Ye[5];
      acc[6] += w4.z*hv*Ye[6];
      acc[7] += w4.z*hv*Ye[7];
    } else {
      acc[0] += w4.z*hv*Ye[0];
      acc[1] += w4.w*hv*Ye[1];
      acc[2] += w4.w*hv*Ye[2];
      acc[3] += w4.w*hv*Ye[3];
      acc[4] += w4.w*hv*Ye[4];
      acc[5] += w4.w*hv*Ye[5];
      acc[6] += w4.w*hv*Ye[6];
      acc[7] += w4.w*hv*Ye[7];
    }
  }
  const float inv = 1.f/16.f;
  float* ap = agg + (size_t)n*2048 + k*16 + mg*8;
  #pragma unroll
  for(int j=0;j<8;++j) ap[j] = acc[j]*inv;
}

// ---------------- mixed (all 16 m per block) + skip / skipT ----------------
__global__ __launch_bounds__(256) void k_mixed2(const float* X, const float* hin, const int* elem,
                                                const float* Wb, const float* Wsk,
                                                float* Out, float* gh, int N, int mode){
  __shared__ float xs[4][2048];
  __shared__ float hs[4][128];
  __shared__ int zs[4];
  int t = threadIdx.x;
  int n0 = blockIdx.x*4;
  for(int q=0;q<4;++q){
    const float4* Xp = (const float4*)(X + (size_t)(n0+q)*2048);
    float4* Xs = (float4*)xs[q];
    Xs[t] = Xp[t]; Xs[t+256] = Xp[t+256];
  }
  if(mode==0 && t<128){
    for(int q=0;q<4;++q) hs[q][t] = hin[(size_t)(n0+q)*KCH + t];
  }
  if(t<4) zs[t]=elem[n0+t];
  __syncthreads();
  int kg = t&31, mg=(t>>5)&3, half=t>>7;
  int k0 = kg*4, m0 = mg*4;
  int q0 = half*2, q1=q0+1;
  float acc0[4][4], acc1[4][4];
  #pragma unroll
  for(int a=0;a<4;++a){
    #pragma unroll
    for(int b=0;b<4;++b){acc0[a][b]=0.f;acc1[a][b]=0.f;}
  }
  for(int s=0;s<KCH;++s){
    float4 x0 = *(const float4*)&xs[q0][s*16+m0];
    float4 x1 = *(const float4*)&xs[q1][s*16+m0];
    #pragma unroll
    for(int mj=0;mj<4;++mj){
      const float4 wv = *(const float4*)&Wb[(size_t)(m0+mj)*16384 + s*128 + k0];
      float xm0 = (mj==0)?x0.x:((mj==1)?x0.y:((mj==2)?x0.z:x0.w));
      float xm1 = (mj==0)?x1.x:((mj==1)?x1.y:((mj==2)?x1.z:x1.w));
      acc0[mj][0]+=xm0*wv.x; acc0[mj][1]+=xm0*wv.y; acc0[mj][2]+=xm0*wv.z; acc0[mj][3]+=xm0*wv.w;
      acc1[mj][0]+=xm1*wv.x; acc1[mj][1]+=xm1*wv.y; acc1[mj][2]+=xm1*wv.z; acc1[mj][3]+=xm1*wv.w;
    }
  }
  if(mode==0 && mg==0){
    const float* W0 = Wsk + (size_t)zs[q0]*16384;
    const float* W1 = Wsk + (size_t)zs[q1]*16384;
    for(int s=0;s<KCH;++s){
      float h0v=hs[q0][s], h1v=hs[q1][s];
      float4 w0 = *(const float4*)&W0[s*128+k0];
      float4 w1 = *(const float4*)&W1[s*128+k0];
      acc0[0][0]+=h0v*w0.x; acc0[0][1]+=h0v*w0.y; acc0[0][2]+=h0v*w0.z; acc0[0][3]+=h0v*w0.w;
      acc1[0][0]+=h1v*w1.x; acc1[0][1]+=h1v*w1.y; acc1[0][2]+=h1v*w1.z; acc1[0][3]+=h1v*w1.w;
    }
  }
  #pragma unroll
  for(int ki=0;ki<4;++ki){
    *(float4*)&Out[(size_t)(n0+q0)*2048 + (k0+ki)*16 + m0] = make_float4(acc0[0][ki],acc0[1][ki],acc0[2][ki],acc0[3][ki]);
    *(float4*)&Out[(size_t)(n0+q1)*2048 + (k0+ki)*16 + m0] = make_float4(acc1[0][ki],acc1[1][ki],acc1[2][ki],acc1[3][ki]);
  }
  if(mode==2 && mg==0){
    const float* W0 = Wsk + (size_t)zs[q0]*16384;
    const float* W1 = Wsk + (size_t)zs[q1]*16384;
    float a0[4]={0,0,0,0}, a1[4]={0,0,0,0};
    for(int s=0;s<KCH;++s){
      float x0v = xs[q0][s*16], x1v = xs[q1][s*16];
      float4 w0 = *(const float4*)&W0[s*128+k0];
      float4 w1 = *(const float4*)&W1[s*128+k0];
      a0[0]+=x0v*w0.x; a0[1]+=x0v*w0.y; a0[2]+=x0v*w0.z; a0[3]+=x0v*w0.w;
      a1[0]+=x1v*w1.x; a1[1]+=x1v*w1.y; a1[2]+=x1v*w1.z; a1[3]+=x1v*w1.w;
    }
    *(float4*)&gh[(size_t)(n0+q0)*KCH + k0] = make_float4(a0[0],a0[1],a0[2],a0[3]);
    *(float4*)&gh[(size_t)(n0+q1)*KCH + k0] = make_float4(a1[0],a1[1],a1[2],a1[3]);
  }
}

// ---------------- polynomial contraction fwd (packed symmetric) ----------------
__global__ __launch_bounds__(256) void k_poly_fwd(const float* A, const float* C1, const float* C2S, const float* P,
                                                  const int* eptr, const int* eidx, float* B){
  __shared__ float Ps[PSZ];
  __shared__ float C2s_[256];
  __shared__ float C1s_[16];
  int t = threadIdx.x;
  int z = blockIdx.x >> 7, c = blockIdx.x & 127;
  size_t cb = (size_t)z*KCH + c;
  for(int i=t;i<PSZ;i+=256) Ps[i] = P[cb*PSZ + i];
  if(t<256) C2s_[t] = C2S[cb*256 + t];
  if(t<16) C1s_[t] = C1[cb*16 + t];
  __syncthreads();
  int s0 = eptr[z], cnt = eptr[z+1]-s0;
  for(int idx=t; idx<cnt; idx+=256){
    int n = eidx[s0+idx];
    float a[16];
    const float4* ap = (const float4*)(A + (size_t)n*2048 + c*16);
    float4 a4;
    a4=ap[0]; a[0]=a4.x;a[1]=a4.y;a[2]=a4.z;a[3]=a4.w;
    a4=ap[1]; a[4]=a4.x;a[5]=a4.y;a[6]=a4.z;a[7]=a4.w;
    a4=ap[2]; a[8]=a4.x;a[9]=a4.y;a[10]=a4.z;a[11]=a4.w;
    a4=ap[3]; a[12]=a4.x;a[13]=a4.y;a[14]=a4.z;a[15]=a4.w;
    float G[16];
    #pragma unroll
    for(int x=0;x<16;++x) G[x]=0.f;
    int pair=0;
    #pragma unroll
    for(int j=0;j<16;++j){
      #pragma unroll
      for(int k=j;k<16;++k){
        float pp = a[j]*a[k];
        const float* Pp = &Ps[pair*16];
        #pragma unroll
        for(int x=0;x<16;++x) G[x] += pp*Pp[x];
        ++pair;
      }
    }
    float b1=0;
    #pragma unroll
    for(int i=0;i<16;++i) b1 += a[i]*C1s_[i];
    float b2=0;
    for(int i=0;i<16;++i){
      float s=0;
      #pragma unroll
      for(int j=0;j<16;++j) s += a[j]*C2s_[i*16+j];
      b2 += a[i]*s;
    }
    float b3o=0;
    #pragma unroll
    for(int x=0;x<16;++x) b3o += a[x]*G[x];
    B[(size_t)n*KCH + c] = b1 + 0.5f*b2 + b3o*(1.f/3.f);
  }
}

// ---------------- polynomial contraction bwd (packed symmetric) ----------------
__global__ __launch_bounds__(256) void k_poly_bwd(const float* A, const float* C1, const float* C2S, const float* P,
                                                  const int* eptr, const int* eidx,
                                                  const float* gBvec, const float* gBbuf, float* gA){
  __shared__ float Ps[PSZ];
  __shared__ float C2s_[256];
  __shared__ float C1s_[16];
  int t = threadIdx.x;
  int z = blockIdx.x >> 7, c = blockIdx.x & 127;
  size_t cb = (size_t)z*KCH + c;
  for(int i=t;i<PSZ;i+=256) Ps[i] = P[cb*PSZ + i];
  if(t<256) C2s_[t] = C2S[cb*256 + t];
  if(t<16) C1s_[t] = C1[cb*16 + t];
  __syncthreads();
  int s0 = eptr[z], cnt = eptr[z+1]-s0;
  for(int idx=t; idx<cnt; idx+=256){
    int n = eidx[s0+idx];
    float a[16];
    const float4* ap = (const float4*)(A + (size_t)n*2048 + c*16);
    float4 a4;
    a4=ap[0]; a[0]=a4.x;a[1]=a4.y;a[2]=a4.z;a[3]=a4.w;
    a4=ap[1]; a[4]=a4.x;a[5]=a4.y;a[6]=a4.z;a[7]=a4.w;
    a4=ap[2]; a[8]=a4.x;a[9]=a4.y;a[10]=a4.z;a[11]=a4.w;
    a4=ap[3]; a[12]=a4.x;a[13]=a4.y;a[14]=a4.z;a[15]=a4.w;
    float gB = gBvec ? gBvec[c] : gBbuf[(size_t)n*KCH + c];
    float G[16];
    #pragma unroll
    for(int x=0;x<16;++x) G[x]=C1s_[x];
    for(int x=0;x<16;++x){
      float s=0;
      #pragma unroll
      for(int b=0;b<16;++b) s += a[b]*C2s_[x*16+b];
      G[x]+=s;
    }
    int pair=0;
    #pragma unroll
    for(int j=0;j<16;++j){
      #pragma unroll
      for(int k=j;k<16;++k){
        float pp = a[j]*a[k];
        const float* Pp = &Ps[pair*16];
        #pragma unroll
        for(int x=0;x<16;++x) G[x] += pp*Pp[x];
        ++pair;
      }
    }
    float* gp = gA + (size_t)n*2048 + c*16;
    #pragma unroll
    for(int x=0;x<16;++x) gp[x] = gB*G[x];
  }
}

// ---------------- edge backward phase A (chunked): gw -> global, ghup, gY.dY -> gvec ----------------
// 2 edges per block, 128 k-threads per edge. Edges [base, base+ce).
__global__ __launch_bounds__(256) void k_edge_gw(const float* gagg, const float* hup, const float* w,
                                                 const float* Y, const float* dY,
                                                 const int* snds, const int* rcvs, int E, int base, int ce,
                                                 float* gw, float* ghup, float* gvec, int do_ghup, int accv){
  __shared__ float Ys[2][16];
  __shared__ float gYp[2][2][16];
  int t = threadIdx.x;
  int le = t>>7, k = t&127;
  int e = base + blockIdx.x*2 + le;
  int elim = base + ce;
  const float inv16 = 1.f/16.f;
  if(t<32){ int l2=t>>4; int ec=base+blockIdx.x*2+l2; if(ec<elim) Ys[l2][t&15] = Y[(size_t)ec*16 + (t&15)]; }
  __syncthreads();
  bool valid = (e<elim);
  int eC = valid ? e : (elim-1);
  int snd = snds[eC], rcv = rcvs[eC];
  float hv = hup[(size_t)snd*KCH + k];
  float4 w4 = ((const float4*)(w + (size_t)eC*512))[k];
  float g[16];
  const float4* gp = (const float4*)(gagg + (size_t)rcv*2048 + k*16);
  float4 v4;
  v4=gp[0]; g[0]=v4.x;g[1]=v4.y;g[2]=v4.z;g[3]=v4.w;
  v4=gp[1]; g[4]=v4.x;g[5]=v4.y;g[6]=v4.z;g[7]=v4.w;
  v4=gp[2]; g[8]=v4.x;g[9]=v4.y;g[10]=v4.z;g[11]=v4.w;
  v4=gp[3]; g[12]=v4.x;g[13]=v4.y;g[14]=v4.z;g[15]=v4.w;
  const float* Yl = Ys[le];
  float p0 = g[0]*Yl[0];
  float p1 = g[1]*Yl[1]+g[2]*Yl[2]+g[3]*Yl[3];
  float p2 = g[4]*Yl[4]+g[5]*Yl[5]+g[6]*Yl[6]+g[7]*Yl[7]+g[8]*Yl[8];
  float p3 = g[9]*Yl[9]+g[10]*Yl[10]+g[11]*Yl[11]+g[12]*Yl[12]+g[13]*Yl[13]+g[14]*Yl[14]+g[15]*Yl[15];
  float hs = hv*inv16;
  ((float4*)(gw + (size_t)(eC-base)*512))[k] = make_float4(p0*hs, p1*hs, p2*hs, p3*hs);
  if(do_ghup && valid){
    float s = (p0*w4.x + p1*w4.y + p2*w4.z + p3*w4.w)*inv16;
    atomicAdd(&ghup[(size_t)snd*KCH+k], s);
  }
  float q[16];
  q[0]=g[0]*w4.x*hv;
  q[1]=g[1]*w4.y*hv; q[2]=g[2]*w4.y*hv; q[3]=g[3]*w4.y*hv;
  q[4]=g[4]*w4.z*hv; q[5]=g[5]*w4.z*hv; q[6]=g[6]*w4.z*hv; q[7]=g[7]*w4.z*hv; q[8]=g[8]*w4.z*hv;
  #pragma unroll
  for(int m=9;m<16;++m) q[m]=g[m]*w4.w*hv;
  #pragma unroll
  for(int m=0;m<16;++m){
    float vv=q[m];
    #pragma unroll
    for(int off2=1; off2<64; off2<<=1) vv += __shfl_xor(vv, off2, 64);
    q[m]=vv;
  }
  if((t&63)==0){
    int wv2 = (t>>6)&1;
    #pragma unroll
    for(int m=0;m<16;++m) gYp[le][wv2][m]=q[m];
  }
  __syncthreads();
  if(t<6){
    int le2 = t/3, jj = t-le2*3;
    int ee = base + blockIdx.x*2 + le2;
    if(ee<elim){
      float s=0;
      #pragma unroll
      for(int m=0;m<16;++m)
        s += (gYp[le2][0][m]+gYp[le2][1][m])*inv16 * dY[(size_t)ee*48 + m*3 + jj];
      if(accv) gvec[(size_t)ee*3+jj] += s;
      else     gvec[(size_t)ee*3+jj]  = s;
    }
  }
}

// ---------------- edge backward phase B (chunked): radial MLP bwd (16 edges/block) ----------------
__global__ __launch_bounds__(256) void k_radial_bwd2(const float* gw, const float* ef, const float* defdr,
                                                     const float* vec, const float* rr,
                                                     const float* Wr1, const float* Wr2,
                                                     const float* Wr2T, const float* Wr3T,
                                                     float* gvec, int E, int base, int ce){
  __shared__ float t1s[16][64];
  __shared__ float gz2s[16][64];
  __shared__ float efS[16][8];
  __shared__ float defS[16][8];
  int t = threadIdx.x;
  int e0 = base + blockIdx.x*16;
  int elim = base + ce;
  int j = t&63, g = t>>6;
  if(t<128){ int el=t>>3, b=t&7; int ec=e0+el;
    if(ec<elim){ efS[el][b]=ef[(size_t)ec*8+b]; defS[el][b]=defdr[(size_t)ec*8+b]; }
    else { efS[el][b]=0.f; defS[el][b]=0.f; } }
  __syncthreads();
  float ds1[4], ds2[4];
  #pragma unroll
  for(int q=0;q<4;++q){
    int el = g*4+q;
    float z=0;
    #pragma unroll
    for(int b=0;b<8;++b) z += efS[el][b]*Wr1[b*64+j];
    t1s[el][j]=siluf(z); ds1[q]=dsiluf(z);
  }
  __syncthreads();
  float gt2[4]={0,0,0,0};
  #pragma unroll
  for(int q=0;q<4;++q){
    int el = g*4+q;
    float z=0;
    for(int i=0;i<64;++i) z += t1s[el][i]*Wr2[i*64+j];
    ds2[q]=dsiluf(z);
  }
  for(int i4=0;i4<128;++i4){
    float wv0 = Wr3T[(i4*4+0)*64+j];
    float wv1 = Wr3T[(i4*4+1)*64+j];
    float wv2 = Wr3T[(i4*4+2)*64+j];
    float wv3 = Wr3T[(i4*4+3)*64+j];
    #pragma unroll
    for(int q=0;q<4;++q){
      int ec = e0 + g*4 + q; if(ec>=elim) ec=elim-1;
      const float4 g4 = *(const float4*)(gw + (size_t)(ec-base)*512 + i4*4);
      gt2[q] += g4.x*wv0 + g4.y*wv1 + g4.z*wv2 + g4.w*wv3;
    }
  }
  #pragma unroll
  for(int q=0;q<4;++q) gz2s[g*4+q][j] = gt2[q]*ds2[q];
  __syncthreads();
  #pragma unroll
  for(int q=0;q<4;++q){
    int el = g*4+q;
    float s=0;
    for(int o=0;o<64;++o) s += gz2s[el][o]*Wr2T[o*64+j];
    float gz1 = s*ds1[q];
    float cj=0;
    #pragma unroll
    for(int b=0;b<8;++b) cj += Wr1[b*64+j]*defS[el][b];
    float p = gz1*cj;
    #pragma unroll
    for(int off2=1;off2<64;off2<<=1) p += __shfl_xor(p,off2,64);
    int ec = e0+el;
    if(j<3 && ec<elim)
      gvec[(size_t)ec*3+j] += p * vec[(size_t)ec*3+j] / rr[ec];
  }
}

// ---------------- FALLBACK fused edge backward (round-4 version) ----------------
__global__ __launch_bounds__(256) void k_edge_bwd2(const float* gagg, const float* hup, const float* w,
                                                   const float* Y, const float* dY,
                                                   const float* vec, const float* rr,
                                                   const float* ef, const float* defdr,
                                                   const float* Wr1, const float* Wr2,
                                                   const float* Wr2T, const float* Wr3T,
                                                   const int* snds, const int* rcvs, int E,
                                                   float* ghup, float* gvec, int do_ghup, int accv){
  __shared__ float Ys[4][16];
  __shared__ float gwS[4][512];
  __shared__ float gYp[4][2][16];
  __shared__ float t1s[4][64];
  __shared__ float gz2s[4][64];
  __shared__ float efS[4][8];
  __shared__ float defS[4][8];
  int t = threadIdx.x;
  int e0 = blockIdx.x*4;
  const float inv16 = 1.f/16.f;
  if(t<64){ int le=t>>4; int ec = e0+le; if(ec<E) Ys[le][t&15] = Y[(size_t)ec*16 + (t&15)]; }
  else if(t<96){ int i=t-64; int le=i>>3; int ec=e0+le; if(ec<E) efS[le][i&7]=ef[(size_t)ec*8+(i&7)]; }
  else if(t<128){ int i=t-96; int le=i>>3; int ec=e0+le; if(ec<E) defS[le][i&7]=defdr[(size_t)ec*8+(i&7)]; }
  __syncthreads();
  for(int rep=0;rep<2;++rep){
    int le = (t>>7) + 2*rep;
    int k = t&127;
    int e = e0+le;
    bool valid = (e<E);
    int eC = valid ? e : (E-1);
    int snd = snds[eC], rcv = rcvs[eC];
    float hv = hup[(size_t)snd*KCH + k];
    float4 w4 = ((const float4*)(w + (size_t)eC*512))[k];
    float g[16];
    const float4* gp = (const float4*)(gagg + (size_t)rcv*2048 + k*16);
    float4 v4;
    v4=gp[0]; g[0]=v4.x;g[1]=v4.y;g[2]=v4.z;g[3]=v4.w;
    v4=gp[1]; g[4]=v4.x;g[5]=v4.y;g[6]=v4.z;g[7]=v4.w;
    v4=gp[2]; g[8]=v4.x;g[9]=v4.y;g[10]=v4.z;g[11]=v4.w;
    v4=gp[3]; g[12]=v4.x;g[13]=v4.y;g[14]=v4.z;g[15]=v4.w;
    const float* Yl = Ys[le];
    float p0 = g[0]*Yl[0];
    float p1 = g[1]*Yl[1]+g[2]*Yl[2]+g[3]*Yl[3];
    float p2 = g[4]*Yl[4]+g[5]*Yl[5]+g[6]*Yl[6]+g[7]*Yl[7]+g[8]*Yl[8];
    float p3 = g[9]*Yl[9]+g[10]*Yl[10]+g[11]*Yl[11]+g[12]*Yl[12]+g[13]*Yl[13]+g[14]*Yl[14]+g[15]*Yl[15];
    float hs = hv*inv16;
    ((float4*)(&gwS[le][k*4]))[0] = make_float4(p0*hs, p1*hs, p2*hs, p3*hs);
    if(do_ghup && valid){
      float s = (p0*w4.x + p1*w4.y + p2*w4.z + p3*w4.w)*inv16;
      atomicAdd(&ghup[(size_t)snd*KCH+k], s);
    }
    float q[16];
    q[0]=g[0]*w4.x*hv;
    q[1]=g[1]*w4.y*hv; q[2]=g[2]*w4.y*hv; q[3]=g[3]*w4.y*hv;
    q[4]=g[4]*w4.z*hv; q[5]=g[5]*w4.z*hv; q[6]=g[6]*w4.z*hv; q[7]=g[7]*w4.z*hv; q[8]=g[8]*w4.z*hv;
    #pragma unroll
    for(int m=9;m<16;++m) q[m]=g[m]*w4.w*hv;
    #pragma unroll
    for(int m=0;m<16;++m){
      float vv=q[m];
      #pragma unroll
      for(int off2=1; off2<64; off2<<=1) vv += __shfl_xor(vv, off2, 64);
      q[m]=vv;
    }
    if((t&63)==0){
      int wv2 = (t>>6)&1;
      #pragma unroll
      for(int m=0;m<16;++m) gYp[le][wv2][m]=q[m];
    }
  }
  __syncthreads();
  {
    int el = t>>6, j = t&63;
    int e = e0+el;
    bool valid = (e<E);
    int eC = valid ? e : (E-1);
    float z1=0;
    #pragma unroll
    for(int b=0;b<8;++b) z1 += efS[el][b]*Wr1[b*64+j];
    float ds1v = dsiluf(z1);
    t1s[el][j] = siluf(z1);
    __syncthreads();
    float z2=0;
    for(int i=0;i<64;++i) z2 += t1s[el][i]*Wr2[i*64+j];
    float ds2v = dsiluf(z2);
    float gt2=0;
    for(int i=0;i<512;++i) gt2 += gwS[el][i]*Wr3T[i*64+j];
    gz2s[el][j] = gt2*ds2v;
    __syncthreads();
    float gz1=0;
    for(int o=0;o<64;++o) gz1 += gz2s[el][o]*Wr2T[o*64+j];
    gz1 *= ds1v;
    float cj=0;
    #pragma unroll
    for(int b=0;b<8;++b) cj += Wr1[b*64+j]*defS[el][b];
    float p = gz1*cj;
    #pragma unroll
    for(int off2=1;off2<64;off2<<=1) p += __shfl_xor(p,off2,64);
    if(j<3 && valid){
      float s = p * vec[(size_t)eC*3+j] / rr[eC];
      #pragma unroll
      for(int m=0;m<16;++m)
        s += (gYp[el][0][m]+gYp[el][1][m])*inv16 * dY[(size_t)eC*48 + m*3 + j];
      if(accv) gvec[(size_t)eC*3+j] += s;
      else     gvec[(size_t)eC*3+j]  = s;
    }
  }
}

// ---------------- energy readout ----------------
__global__ void k_energy(const float* h2, const float* Wro, const float* AE,
                         const int* elem, const int* batch, float* out, int N){
  int n = blockIdx.x*256 + threadIdx.x;
  if(n>=N) return;
  float s=0;
  for(int k=0;k<KCH;++k) s += h2[(size_t)n*KCH+k]*Wro[k];
  s += AE[elem[n]];
  atomicAdd(&out[batch[n]], s);
}

// ---------------- forces scatter ----------------
__global__ void k_forces(const float* gvec, const int* snds, const int* rcvs, int E, float* fout){
  int i = blockIdx.x*256 + threadIdx.x;
  if(i>=E*3) return;
  int e = i/3, j = i - e*3;
  float g = gvec[i];
  atomicAdd(&fout[(size_t)snds[e]*3+j], g);
  atomicAdd(&fout[(size_t)rcvs[e]*3+j], -g);
}

// =============================================================
extern "C" void kernel_launch(void* const* d_in, const int* in_sizes, int n_in,
                              void* d_out, int out_size, void* d_ws, size_t ws_size,
                              hipStream_t stream){
  const float* attrs  = (const float*)d_in[0];
  const float* pos    = (const float*)d_in[1];
  const float* shifts = (const float*)d_in[2];
  const float* AE     = (const float*)d_in[3];
  const float* Wemb   = (const float*)d_in[4];
  const float* Wup    = (const float*)d_in[5];
  const float* Wr1    = (const float*)d_in[6];
  const float* Wr2    = (const float*)d_in[7];
  const float* Wr3    = (const float*)d_in[8];
  const float* Wlin   = (const float*)d_in[9];
  const float* Wskip  = (const float*)d_in[10];
  const float* U1     = (const float*)d_in[11];
  const float* U2     = (const float*)d_in[12];
  const float* U3     = (const float*)d_in[13];
  const float* Wc1    = (const float*)d_in[14];
  const float* Wc2    = (const float*)d_in[15];
  const float* Wc3    = (const float*)d_in[16];
  const float* Wprod  = (const float*)d_in[17];
  const float* Wro    = (const float*)d_in[18];
  const int*   ei     = (const int*)d_in[19];
  const int*   batch  = (const int*)d_in[20];
  int N = in_sizes[1]/3;
  int E = in_sizes[19]/2;
  float* out = (float*)d_out;
  int G = out_size - 3*N;

  char* base = (char*)d_ws;
  size_t off = 0;
  auto alloc = [&](size_t nbytes)->void*{
    void* p = base + off;
    off += (nbytes + 255) & ~(size_t)255;
    return p;
  };
  int* elem = (int*)alloc((size_t)N*4);
  int* rptr = (int*)alloc((size_t)(N+1)*4);
  // zeroed counter block (contiguous)
  int* rcnt = (int*)alloc((size_t)N*4);
  int* rcur = (int*)alloc((size_t)N*4);
  int* ecnt = (int*)alloc((size_t)NELEM*4);
  int* ecur = (int*)alloc((size_t)NELEM*4);
  size_t zspan = (size_t)((base+off) - (char*)rcnt) / 4;
  int* ridx = (int*)alloc((size_t)E*4);
  int* eptr = (int*)alloc((size_t)(NELEM+1)*4);
  int* eidx = (int*)alloc((size_t)N*4);
  int* snds = (int*)alloc((size_t)E*4);
  int* rcvs = (int*)alloc((size_t)E*4);
  float* h0   = (float*)alloc((size_t)N*KCH*4);
  float* h1   = (float*)alloc((size_t)N*KCH*4);
  float* h2   = (float*)alloc((size_t)N*KCH*4);
  float* hup0 = (float*)alloc((size_t)N*KCH*4);
  float* hup1 = (float*)alloc((size_t)N*KCH*4);
  float* vecb = (float*)alloc((size_t)E*3*4);
  float* rb   = (float*)alloc((size_t)E*4);
  float* Yb   = (float*)alloc((size_t)E*16*4);
  float* dYb  = (float*)alloc((size_t)E*48*4);
  float* efb  = (float*)alloc((size_t)E*8*4);
  float* defb = (float*)alloc((size_t)E*8*4);
  float* wb   = (float*)alloc((size_t)E*512*4);
  float* A0   = (float*)alloc((size_t)N*2048*4);
  float* A1   = (float*)alloc((size_t)N*2048*4);
  float* aggb = (float*)alloc((size_t)N*2048*4);
  float* gAb  = (float*)alloc((size_t)N*2048*4);
  float* Bbuf = (float*)alloc((size_t)N*KCH*4);
  float* gh1  = (float*)alloc((size_t)N*KCH*4);
  float* ghup = (float*)alloc((size_t)N*KCH*4);
  float* gB0b = (float*)alloc((size_t)N*KCH*4);
  float* gB1v = (float*)alloc((size_t)KCH*4);
  float* gvecb= (float*)alloc((size_t)E*3*4);
  float* C1b  = (float*)alloc((size_t)NELEM*KCH*16*4);
  float* C2Sb = (float*)alloc((size_t)NELEM*KCH*256*4);
  float* Pb   = (float*)alloc((size_t)NELEM*KCH*PSZ*4);
  float* U2s  = (float*)alloc(1024*4);
  float* U3s  = (float*)alloc(32768*4);
  float* WupT1   = (float*)alloc(16384*4);
  float* WprodT0 = (float*)alloc(16384*4);
  float* WskipT1 = (float*)alloc((size_t)NELEM*16384*4);
  float* Wbig0  = (float*)alloc((size_t)16*16384*4);
  float* Wbig1  = (float*)alloc((size_t)16*16384*4);
  float* WbigT0 = (float*)alloc((size_t)16*16384*4);
  float* WbigT1 = (float*)alloc((size_t)16*16384*4);
  float* Wr3T0   = (float*)alloc(32768*4);
  float* Wr3T1   = (float*)alloc(32768*4);
  float* Wr2T0   = (float*)alloc(4096*4);
  float* Wr2T1   = (float*)alloc(4096*4);
  if(off > ws_size) return; // insufficient workspace

  // PRIORITY 1: gw buffer for split edge backward (full, else half-chunk)
  float* gwb = nullptr; int gw_edges = 0;
  {
    size_t fullB = (size_t)E*512*4;
    int halfE = ((E/2 + 15)/16)*16; if(halfE > E) halfE = E;
    if(off + fullB <= ws_size){ gwb = (float*)alloc(fullB); gw_edges = E; }
    else if(off + (size_t)halfE*512*4 <= ws_size){ gwb = (float*)alloc((size_t)halfE*512*4); gw_edges = halfE; }
  }
  // PRIORITY 2: second C-tensor set (layer-1)
  float *C1_1=C1b, *C2_1=C2Sb, *P_1=Pb; int have_c2 = 0;
  {
    size_t need = ((size_t)NELEM*KCH*16 + (size_t)NELEM*KCH*256 + (size_t)NELEM*KCH*PSZ)*4 + 1024;
    if(off + need <= ws_size){
      C1_1 = (float*)alloc((size_t)NELEM*KCH*16*4);
      C2_1 = (float*)alloc((size_t)NELEM*KCH*256*4);
      P_1  = (float*)alloc((size_t)NELEM*KCH*PSZ*4);
      have_c2 = 1;
    }
  }
  // PRIORITY 3: second w buffer (layer-1 w)
  float* wb1 = wb; int have_wb1 = 0;
  if(off + (size_t)E*512*4 <= ws_size){ wb1 = (float*)alloc((size_t)E*512*4); have_wb1 = 1; }

  const int KK = KCH*KCH;           // 16384
  dim3 b256(256), b128(128);
  #define GR(n) dim3(((n)+255)/256)

  // zeros (counters fused; out; ghup)
  k_zero<<<GR(out_size),b256,0,stream>>>(out, out_size);
  k_zero<<<GR((int)zspan),b256,0,stream>>>((float*)rcnt, (int)zspan);
  k_zero<<<GR(N*KCH),b256,0,stream>>>(ghup, N*KCH);

  // elem + embed
  k_elem<<<GR(N),b256,0,stream>>>(attrs, elem, N);
  k_h0<<<GR(N*KCH),b256,0,stream>>>(Wemb, elem, h0, N);

  // CSR by recv
  k_hist<<<GR(E),b256,0,stream>>>(ei+E, rcnt, E);
  k_scan<<<1,b256,0,stream>>>(rcnt, rptr, N);
  k_scatter<<<GR(E),b256,0,stream>>>(ei+E, rptr, rcur, ridx, E);
  // node lists by element
  k_hist<<<GR(N),b256,0,stream>>>(elem, ecnt, N);
  k_scan<<<1,b256,0,stream>>>(ecnt, eptr, NELEM);
  k_scatter<<<GR(N),b256,0,stream>>>(elem, eptr, ecur, eidx, N);

  // fused weight prep
  k_prep<<<GR(PREP_ITEMS),b256,0,stream>>>(Wup, Wprod, Wskip, Wlin, Wr2, Wr3, U2, U3,
                                           WupT1, WprodT0, WskipT1,
                                           Wbig0, Wbig1, WbigT0, WbigT1,
                                           Wr3T0, Wr3T1, Wr2T0, Wr2T1, U2s, U3s);
  k_gB1<<<1,b128,0,stream>>>(Wro, Wprod + KK, gB1v);

  // edge geometry (sorted order)
  k_edge_geom<<<GR(E),b256,0,stream>>>(pos, shifts, ei, ridx, E, snds, rcvs,
                                       vecb, rb, Yb, dYb, efb, defb);

  dim3 mmG((N+7)/8);
  dim3 mxG((N+3)/4);
  dim3 polyG(NELEM*KCH);
  dim3 rwG((E+15)/16);
  dim3 ebG((E+3)/4);

  // ---------- layer 0 forward ----------
  k_ctens<<<GR(CTENS_ITEMS),b256,0,stream>>>(U1, U2s, U3s, Wc1, Wc2, Wc3, C1b, C2Sb, Pb);
  k_mm<<<mmG,b128,0,stream>>>(h0, Wup, hup0, N, 0);
  k_radial_w<<<rwG,b256,0,stream>>>(efb, Wr1, Wr2, Wr3, wb, E);
  k_gather<<<dim3(N),b256,0,stream>>>(hup0, wb, Yb, rptr, snds, aggb, E);
  k_mixed2<<<mxG,b256,0,stream>>>(aggb, h0, elem, Wbig0, Wskip, A0, nullptr, N, 0);
  k_poly_fwd<<<polyG,b256,0,stream>>>(A0, C1b, C2Sb, Pb, eptr, eidx, Bbuf);
  k_mm<<<mmG,b128,0,stream>>>(Bbuf, Wprod, h1, N, 0);

  // ---------- layer 1 forward ----------
  k_ctens<<<GR(CTENS_ITEMS),b256,0,stream>>>(U1, U2s, U3s,
                                             Wc1 + NELEM*2*KCH, Wc2 + NELEM*4*KCH, Wc3 + NELEM*8*KCH,
                                             C1_1, C2_1, P_1);
  k_mm<<<mmG,b128,0,stream>>>(h1, Wup + KK, hup1, N, 0);
  k_radial_w<<<rwG,b256,0,stream>>>(efb, Wr1 + 512, Wr2 + 4096, Wr3 + 32768, wb1, E);
  k_gather<<<dim3(N),b256,0,stream>>>(hup1, wb1, Yb, rptr, snds, aggb, E);
  k_mixed2<<<mxG,b256,0,stream>>>(aggb, h1, elem, Wbig1, Wskip + (size_t)NELEM*KK, A1, nullptr, N, 0);
  k_poly_fwd<<<polyG,b256,0,stream>>>(A1, C1_1, C2_1, P_1, eptr, eidx, Bbuf);
  k_mm<<<mmG,b128,0,stream>>>(Bbuf, Wprod + KK, h2, N, 0);

  // energy
  k_energy<<<GR(N),b256,0,stream>>>(h2, Wro, AE, elem, batch, out, N);

  // ---------- layer 1 backward ----------
  k_poly_bwd<<<polyG,b256,0,stream>>>(A1, C1_1, C2_1, P_1, eptr, eidx, gB1v, nullptr, gAb);
  k_mixed2<<<mxG,b256,0,stream>>>(gAb, nullptr, elem, WbigT1, WskipT1, aggb, gh1, N, 2);
  if(gwb){
    for(int cb=0; cb<E; cb+=gw_edges){
      int ce = (E-cb < gw_edges) ? (E-cb) : gw_edges;
      k_edge_gw<<<dim3((ce+1)/2),b256,0,stream>>>(aggb, hup1, wb1, Yb, dYb, snds, rcvs, E, cb, ce,
                                                  gwb, ghup, gvecb, 1, 0);
      k_radial_bwd2<<<dim3((ce+15)/16),b256,0,stream>>>(gwb, efb, defb, vecb, rb,
                                                        Wr1 + 512, Wr2 + 4096, Wr2T1, Wr3T1,
                                                        gvecb, E, cb, ce);
    }
  } else {
    k_edge_bwd2<<<ebG,b256,0,stream>>>(aggb, hup1, wb1, Yb, dYb, vecb, rb, efb, defb,
                                       Wr1 + 512, Wr2 + 4096, Wr2T1, Wr3T1, snds, rcvs, E,
                                       ghup, gvecb, 1, 0);
  }
  k_mm<<<mmG,b128,0,stream>>>(ghup, WupT1, gh1, N, 1);

  // ---------- layer 0 backward ----------
  if(!have_c2)
    k_ctens<<<GR(CTENS_ITEMS),b256,0,stream>>>(U1, U2s, U3s, Wc1, Wc2, Wc3, C1b, C2Sb, Pb);
  k_mm<<<mmG,b128,0,stream>>>(gh1, WprodT0, gB0b, N, 0);
  k_poly_bwd<<<polyG,b256,0,stream>>>(A0, C1b, C2Sb, Pb, eptr, eidx, nullptr, gB0b, gAb);
  k_mixed2<<<mxG,b256,0,stream>>>(gAb, nullptr, elem, WbigT0, nullptr, aggb, nullptr, N, 1);
  if(!have_wb1)
    k_radial_w<<<rwG,b256,0,stream>>>(efb, Wr1, Wr2, Wr3, wb, E);
  if(gwb){
    for(int cb=0; cb<E; cb+=gw_edges){
      int ce = (E-cb < gw_edges) ? (E-cb) : gw_edges;
      k_edge_gw<<<dim3((ce+1)/2),b256,0,stream>>>(aggb, hup0, wb, Yb, dYb, snds, rcvs, E, cb, ce,
                                                  gwb, ghup, gvecb, 0, 1);
      k_radial_bwd2<<<dim3((ce+15)/16),b256,0,stream>>>(gwb, efb, defb, vecb, rb,
                                                        Wr1, Wr2, Wr2T0, Wr3T0,
                                                        gvecb, E, cb, ce);
    }
  } else {
    k_edge_bwd2<<<ebG,b256,0,stream>>>(aggb, hup0, wb, Yb, dYb, vecb, rb, efb, defb,
                                       Wr1, Wr2, Wr2T0, Wr3T0, snds, rcvs, E,
                                       ghup, gvecb, 0, 1);
  }

  // forces
  k_forces<<<GR(E*3),b256,0,stream>>>(gvecb, snds, rcvs, E, out + G);
  #undef GR
}

// Round 8
// 1717.073 us; speedup vs baseline: 1.4322x; 1.4322x over previous
//
#include <hip/hip_runtime.h>
#include <math.h>

#define KCH 128
#define NELEM 10
#define NPAIR 136   // 16*17/2
#define PSZ   2176  // NPAIR*16

__device__ __forceinline__ int lidxf(int m){ return (m==0)?0:((m<4)?1:((m<9)?2:3)); }
__device__ __forceinline__ float siluf(float z){ return z/(1.f+expf(-z)); }
__device__ __forceinline__ float dsiluf(float z){ float s=1.f/(1.f+expf(-z)); return s*(1.f+z*(1.f-s)); }

// ---------------- utility ----------------
__global__ void k_zero(float* p, int n){
  int i = blockIdx.x*256 + threadIdx.x;
  if(i<n) p[i]=0.f;
}

__global__ void k_elem(const float* attrs, int* elem, int N){
  int n = blockIdx.x*256 + threadIdx.x;
  if(n>=N) return;
  int z=0;
  for(int e=0;e<NELEM;++e) if(attrs[n*NELEM+e] > 0.5f) z=e;
  elem[n]=z;
}

__global__ void k_h0(const float* Wemb, const int* elem, float* h0, int N){
  int i = blockIdx.x*256 + threadIdx.x;
  if(i>=N*KCH) return;
  int n = i>>7, k = i&127;
  h0[i] = Wemb[elem[n]*KCH + k];
}

__global__ void k_hist(const int* keys, int* cnt, int n){
  int i = blockIdx.x*256 + threadIdx.x;
  if(i<n) atomicAdd(&cnt[keys[i]],1);
}

__global__ void k_scan(const int* cnt, int* ptr, int n){
  __shared__ int part[257];
  int t = threadIdx.x;
  int csz = (n+255)/256;
  int lo = t*csz, hi = (t+1)*csz; if(hi>n) hi=n;
  int s=0;
  for(int i=lo;i<hi;++i) s+=cnt[i];
  part[t]=s; __syncthreads();
  if(t==0){ int acc=0; for(int i=0;i<256;++i){ int v=part[i]; part[i]=acc; acc+=v; } part[256]=acc; }
  __syncthreads();
  int acc = part[t];
  for(int i=lo;i<hi;++i){ ptr[i]=acc; acc+=cnt[i]; }
  if(t==255) ptr[n]=part[256];
}

__global__ void k_scatter(const int* keys, const int* ptr, int* cur, int* idx, int n){
  int i = blockIdx.x*256 + threadIdx.x;
  if(i>=n) return;
  int k = keys[i];
  int p = atomicAdd(&cur[k],1);
  idx[ptr[k]+p] = i;
}

// ---------------- fused weight prep ----------------
__global__ void k_prep(const float* Wup, const float* Wprod, const float* Wskip, const float* Wlin,
                       const float* Wr2, const float* Wr3, const float* U2, const float* U3,
                       float* WupT1, float* WprodT0, float* WskipT1,
                       float* Wbig0, float* Wbig1, float* WbigT0, float* WbigT1,
                       float* Wr3T0, float* Wr3T1, float* Wr2T0, float* Wr2T1,
                       float* U2s, float* U3s){
  int i = blockIdx.x*256 + threadIdx.x;
  const int KK = 16384;
  if(i < KK){ int r=i>>7, c=i&127; WupT1[c*128+r] = Wup[KK + i]; return; }
  i -= KK;
  if(i < KK){ int r=i>>7, c=i&127; WprodT0[c*128+r] = Wprod[i]; return; }
  i -= KK;
  if(i < NELEM*KK){ int mat=i>>14, rc=i&16383, r=rc>>7, c=rc&127;
    WskipT1[mat*KK + c*128 + r] = Wskip[(size_t)NELEM*KK + i]; return; }
  i -= NELEM*KK;
  if(i < 16*KK){ int m=i>>14, sk=i&16383; Wbig0[i] = Wlin[lidxf(m)*KK + sk]; return; }
  i -= 16*KK;
  if(i < 16*KK){ int m=i>>14, sk=i&16383; Wbig1[i] = Wlin[4*KK + lidxf(m)*KK + sk]; return; }
  i -= 16*KK;
  if(i < 16*KK){ int m=i>>14, sk=i&16383, s=sk>>7, k=sk&127; WbigT0[i] = Wlin[lidxf(m)*KK + k*128 + s]; return; }
  i -= 16*KK;
  if(i < 16*KK){ int m=i>>14, sk=i&16383, s=sk>>7, k=sk&127; WbigT1[i] = Wlin[4*KK + lidxf(m)*KK + k*128 + s]; return; }
  i -= 16*KK;
  if(i < 32768){ int r=i>>9, c=i&511; Wr3T0[c*64+r] = Wr3[i]; return; }
  i -= 32768;
  if(i < 32768){ int r=i>>9, c=i&511; Wr3T1[c*64+r] = Wr3[32768 + i]; return; }
  i -= 32768;
  if(i < 4096){ int r=i>>6, c=i&63; Wr2T0[c*64+r] = Wr2[i]; return; }
  i -= 4096;
  if(i < 4096){ int r=i>>6, c=i&63; Wr2T1[c*64+r] = Wr2[4096 + i]; return; }
  i -= 4096;
  if(i < 1024){ int p=i&3, b=(i>>2)&15, a=(i>>6)&15;
    U2s[i] = U2[a*64+b*4+p] + U2[b*64+a*4+p]; return; }
  i -= 1024;
  if(i < 32768){
    int p=i&7, c=(i>>3)&15, b=(i>>7)&15, a=(i>>11)&15;
    U3s[i] = U3[a*2048+b*128+c*8+p] + U3[a*2048+c*128+b*8+p]
           + U3[b*2048+a*128+c*8+p] + U3[b*2048+c*128+a*8+p]
           + U3[c*2048+a*128+b*8+p] + U3[c*2048+b*128+a*8+p];
    return;
  }
}
#define PREP_ITEMS (16384*76 + 32768*2 + 4096*2 + 1024 + 32768)

// ---------------- fused contracted tensors (per layer) ----------------
__global__ void k_ctens(const float* U1, const float* U2s, const float* U3s,
                        const float* Wc1l, const float* Wc2l, const float* Wc3l,
                        float* C1, float* C2S, float* P){
  int i = blockIdx.x*256 + threadIdx.x;
  if(i < NELEM*KCH*16){
    int a=i&15, c=(i>>4)&127, z=i>>11;
    float s=0;
    for(int p=0;p<2;++p) s += U1[a*2+p]*Wc1l[z*2*KCH + p*KCH + c];
    C1[i]=s; return;
  }
  i -= NELEM*KCH*16;
  if(i < NELEM*KCH*256){
    int ab=i&255, c=(i>>8)&127, z=i>>15;
    float s=0;
    for(int p=0;p<4;++p) s += U2s[ab*4+p]*Wc2l[z*4*KCH + p*KCH + c];
    C2S[i]=s; return;
  }
  i -= NELEM*KCH*256;
  if(i < NELEM*KCH*PSZ){
    int x = i & 15;
    int t2 = i >> 4;
    int pair = t2 % NPAIR;
    int cz = t2 / NPAIR;
    int c = cz & 127, z = cz >> 7;
    int j=0, rem=pair;
    while(rem >= 16-j){ rem -= 16-j; ++j; }
    int k = j + rem;
    const float* u = U3s + (size_t)j*2048 + k*128 + x*8;
    float s=0;
    #pragma unroll
    for(int p=0;p<8;++p) s += u[p]*Wc3l[z*8*KCH + p*KCH + c];
    if(j==k) s *= 0.5f;
    P[i] = s; return;
  }
}
#define CTENS_ITEMS (NELEM*KCH*16 + NELEM*KCH*256 + NELEM*KCH*PSZ)

__global__ void k_gB1(const float* Wro, const float* Wprod1, float* gB1){
  int c = threadIdx.x;
  float s=0;
  for(int h=0;h<KCH;++h) s += Wro[h]*Wprod1[c*KCH+h];
  gB1[c]=s;
}

// ---------------- edge geometry (writes in recv-sorted order) ----------------
__global__ void k_edge_geom(const float* pos, const float* shifts, const int* ei, const int* ridx, int E,
                            int* snds, int* rcvs,
                            float* vec, float* rr, float* Y, float* dY, float* ef, float* defdr){
  int i = blockIdx.x*256 + threadIdx.x;
  if(i>=E) return;
  int e = ridx[i];
  int s = ei[e], rc = ei[E+e];
  snds[i]=s; rcvs[i]=rc;
  float vx = pos[rc*3+0]-pos[s*3+0]+shifts[e*3+0];
  float vy = pos[rc*3+1]-pos[s*3+1]+shifts[e*3+1];
  float vz = pos[rc*3+2]-pos[s*3+2]+shifts[e*3+2];
  float r2 = vx*vx+vy*vy+vz*vz + 1e-12f;
  float n = sqrtf(r2);
  float inv_n = 1.f/n;
  float x = vx*inv_n, y = vy*inv_n, z = vz*inv_n;
  vec[i*3+0]=vx; vec[i*3+1]=vy; vec[i*3+2]=vz; rr[i]=n;
  const float s3=1.7320508075688772f, s15=3.8729833462074170f, s5=2.2360679774997896f;
  const float s70=8.3666002653407556f, s105=10.2469507659595980f, s42=6.4807406984078604f, s7=2.6457513110645907f;
  float Yv[16], d0[16], d1[16], d2[16];
  Yv[0]=1.f; d0[0]=0;d1[0]=0;d2[0]=0;
  Yv[1]=s3*x; d0[1]=s3; d1[1]=0; d2[1]=0;
  Yv[2]=s3*y; d0[2]=0; d1[2]=s3; d2[2]=0;
  Yv[3]=s3*z; d0[3]=0; d1[3]=0; d2[3]=s3;
  Yv[4]=s15*x*y; d0[4]=s15*y; d1[4]=s15*x; d2[4]=0;
  Yv[5]=s15*y*z; d0[5]=0; d1[5]=s15*z; d2[5]=s15*y;
  Yv[6]=0.5f*s5*(3.f*z*z-1.f); d0[6]=0; d1[6]=0; d2[6]=3.f*s5*z;
  Yv[7]=s15*x*z; d0[7]=s15*z; d1[7]=0; d2[7]=s15*x;
  Yv[8]=0.5f*s15*(x*x-y*y); d0[8]=s15*x; d1[8]=-s15*y; d2[8]=0;
  Yv[9]=0.25f*s70*y*(3.f*x*x-y*y); d0[9]=1.5f*s70*x*y; d1[9]=0.75f*s70*(x*x-y*y); d2[9]=0;
  Yv[10]=s105*x*y*z; d0[10]=s105*y*z; d1[10]=s105*x*z; d2[10]=s105*x*y;
  Yv[11]=0.25f*s42*y*(5.f*z*z-1.f); d0[11]=0; d1[11]=0.25f*s42*(5.f*z*z-1.f); d2[11]=2.5f*s42*y*z;
  Yv[12]=0.5f*s7*z*(5.f*z*z-3.f); d0[12]=0; d1[12]=0; d2[12]=0.5f*s7*(15.f*z*z-3.f);
  Yv[13]=0.25f*s42*x*(5.f*z*z-1.f); d0[13]=0.25f*s42*(5.f*z*z-1.f); d1[13]=0; d2[13]=2.5f*s42*x*z;
  Yv[14]=0.5f*s105*z*(x*x-y*y); d0[14]=s105*x*z; d1[14]=-s105*y*z; d2[14]=0.5f*s105*(x*x-y*y);
  Yv[15]=0.25f*s70*x*(3.f*x*x-y*y); d0[15]=0.25f*s70*(9.f*x*x-y*y); d1[15]=-0.5f*s70*x*y; d2[15]=0;
  #pragma unroll
  for(int m=0;m<16;++m){
    float dm = d0[m]*x + d1[m]*y + d2[m]*z;
    dY[(size_t)i*48 + m*3 + 0] = (d0[m]-dm*x)*inv_n;
    dY[(size_t)i*48 + m*3 + 1] = (d1[m]-dm*y)*inv_n;
    dY[(size_t)i*48 + m*3 + 2] = (d2[m]-dm*z)*inv_n;
    Y[(size_t)i*16+m] = Yv[m];
  }
  const float c0 = 0.63245553203367587f; // sqrt(2/5)
  float rp = n + 1e-9f;
  float u = n*0.2f;
  float f, dfdr;
  if(u < 1.f){
    float u2=u*u, u4=u2*u2, u5=u4*u, u6=u5*u, u7=u6*u;
    f = 1.f - 21.f*u5 + 35.f*u6 - 15.f*u7;
    float dfdu = -105.f*u4 + 210.f*u5 - 105.f*u6;
    dfdr = dfdu*0.2f;
  } else { f=0.f; dfdr=0.f; }
  for(int b=0;b<8;++b){
    float kn = (float)(b+1)*0.62831853071795865f; // pi/5
    float sr = sinf(kn*n), cr = cosf(kn*n);
    float bess = c0*sr/rp;
    float dbess = c0*(kn*cr/rp - sr/(rp*rp));
    ef[(size_t)i*8+b] = bess*f;
    defdr[(size_t)i*8+b] = dbess*f + bess*dfdr;
  }
}

// ---------------- small row-block matmul ----------------
__global__ __launch_bounds__(128) void k_mm(const float* X, const float* W, float* Out, int N, int acc){
  __shared__ float xs[8][KCH];
  int t = threadIdx.x;
  int n0 = blockIdx.x*8;
  for(int j=0;j<8;++j){ int n=n0+j; xs[j][t] = (n<N)? X[(size_t)n*KCH+t] : 0.f; }
  __syncthreads();
  float a[8] = {0,0,0,0,0,0,0,0};
  for(int s=0;s<KCH;++s){
    float wv = W[s*KCH + t];
    #pragma unroll
    for(int j=0;j<8;++j) a[j] += xs[j][s]*wv;
  }
  for(int j=0;j<8;++j){
    int n=n0+j;
    if(n<N){ if(acc) Out[(size_t)n*KCH+t] += a[j]; else Out[(size_t)n*KCH+t] = a[j]; }
  }
}

// ---------------- radial MLP -> w (E x 512, sorted order) ----------------
__global__ __launch_bounds__(256) void k_radial_w(const float* ef, const float* Wr1, const float* Wr2, const float* Wr3,
                                                  float* w, int E){
  __shared__ float t1s[16][64];
  __shared__ float t2s[16][64];
  int t = threadIdx.x;
  int e0 = blockIdx.x*16;
  for(int it=0; it<4; ++it){
    int item = t + it*256;
    int el = item>>6, j = item&63;
    float z=0;
    if(e0+el < E){
      const float* efe = ef + (size_t)(e0+el)*8;
      #pragma unroll
      for(int b=0;b<8;++b) z += efe[b]*Wr1[b*64+j];
    }
    t1s[el][j] = siluf(z);
  }
  __syncthreads();
  for(int it=0; it<4; ++it){
    int item = t + it*256;
    int el = item>>6, j = item&63;
    float z=0;
    #pragma unroll
    for(int i=0;i<64;++i) z += t1s[el][i]*Wr2[i*64+j];
    t2s[el][j] = siluf(z);
  }
  __syncthreads();
  float a0[16], a1[16];
  #pragma unroll
  for(int el=0;el<16;++el){ a0[el]=0.f; a1[el]=0.f; }
  for(int j=0;j<64;++j){
    float wa = Wr3[j*512 + t];
    float wb = Wr3[j*512 + t + 256];
    #pragma unroll
    for(int el=0;el<16;++el){
      float tv = t2s[el][j];
      a0[el] += tv*wa;
      a1[el] += tv*wb;
    }
  }
  for(int el=0;el<16;++el){
    if(e0+el < E){
      w[(size_t)(e0+el)*512 + t] = a0[el];
      w[(size_t)(e0+el)*512 + t + 256] = a1[el];
    }
  }
}

// ---------------- message aggregation ----------------
__global__ __launch_bounds__(256) void k_gather(const float* hup, const float* w, const float* Y,
                                                const int* rptr, const int* snds,
                                                float* agg, int E){
  int n = blockIdx.x;
  int t = threadIdx.x;
  int k = t & 127, mg = t >> 7;
  float acc[8] = {0,0,0,0,0,0,0,0};
  int s0 = rptr[n], s1 = rptr[n+1];
  for(int i=s0;i<s1;++i){
    int snd = snds[i];
    float hv = hup[(size_t)snd*KCH + k];
    float4 w4 = ((const float4*)(w + (size_t)i*512))[k];
    const float* Ye = Y + (size_t)i*16 + mg*8;
    if(mg==0){
      acc[0] += w4.x*hv*Ye[0];
      acc[1] += w4.y*hv*Ye[1];
      acc[2] += w4.y*hv*Ye[2];
      acc[3] += w4.y*hv*Ye[3];
      acc[4] += w4.z*hv*Ye[4];
      acc[5] += w4.z*hv*Ye[5];
      acc[6] += w4.z*hv*Ye[6];
      acc[7] += w4.z*hv*Ye[7];
    } else {
      acc[0] += w4.z*hv*Ye[0];
      acc[1] += w4.w*hv*Ye[1];
      acc[2] += w4.w*hv*Ye[2];
      acc[3] += w4.w*hv*Ye[3];
      acc[4] += w4.w*hv*Ye[4];
      acc[5] += w4.w*hv*Ye[5];
      acc[6] += w4.w*hv*Ye[6];
      acc[7] += w4.w*hv*Ye[7];
    }
  }
  const float inv = 1.f/16.f;
  float* ap = agg + (size_t)n*2048 + k*16 + mg*8;
  #pragma unroll
  for(int j=0;j<8;++j) ap[j] = acc[j]*inv;
}

// ---------------- mixed (all 16 m per block) + skip / skipT ----------------
__global__ __launch_bounds__(256) void k_mixed2(const float* X, const float* hin, const int* elem,
                                                const float* Wb, const float* Wsk,
                                                float* Out, float* gh, int N, int mode){
  __shared__ float xs[4][2048];
  __shared__ float hs[4][128];
  __shared__ int zs[4];
  int t = threadIdx.x;
  int n0 = blockIdx.x*4;
  for(int q=0;q<4;++q){
    const float4* Xp = (const float4*)(X + (size_t)(n0+q)*2048);
    float4* Xs = (float4*)xs[q];
    Xs[t] = Xp[t]; Xs[t+256] = Xp[t+256];
  }
  if(mode==0 && t<128){
    for(int q=0;q<4;++q) hs[q][t] = hin[(size_t)(n0+q)*KCH + t];
  }
  if(t<4) zs[t]=elem[n0+t];
  __syncthreads();
  int kg = t&31, mg=(t>>5)&3, half=t>>7;
  int k0 = kg*4, m0 = mg*4;
  int q0 = half*2, q1=q0+1;
  float acc0[4][4], acc1[4][4];
  #pragma unroll
  for(int a=0;a<4;++a){
    #pragma unroll
    for(int b=0;b<4;++b){acc0[a][b]=0.f;acc1[a][b]=0.f;}
  }
  for(int s=0;s<KCH;++s){
    float4 x0 = *(const float4*)&xs[q0][s*16+m0];
    float4 x1 = *(const float4*)&xs[q1][s*16+m0];
    #pragma unroll
    for(int mj=0;mj<4;++mj){
      const float4 wv = *(const float4*)&Wb[(size_t)(m0+mj)*16384 + s*128 + k0];
      float xm0 = (mj==0)?x0.x:((mj==1)?x0.y:((mj==2)?x0.z:x0.w));
      float xm1 = (mj==0)?x1.x:((mj==1)?x1.y:((mj==2)?x1.z:x1.w));
      acc0[mj][0]+=xm0*wv.x; acc0[mj][1]+=xm0*wv.y; acc0[mj][2]+=xm0*wv.z; acc0[mj][3]+=xm0*wv.w;
      acc1[mj][0]+=xm1*wv.x; acc1[mj][1]+=xm1*wv.y; acc1[mj][2]+=xm1*wv.z; acc1[mj][3]+=xm1*wv.w;
    }
  }
  if(mode==0 && mg==0){
    const float* W0 = Wsk + (size_t)zs[q0]*16384;
    const float* W1 = Wsk + (size_t)zs[q1]*16384;
    for(int s=0;s<KCH;++s){
      float h0v=hs[q0][s], h1v=hs[q1][s];
      float4 w0 = *(const float4*)&W0[s*128+k0];
      float4 w1 = *(const float4*)&W1[s*128+k0];
      acc0[0][0]+=h0v*w0.x; acc0[0][1]+=h0v*w0.y; acc0[0][2]+=h0v*w0.z; acc0[0][3]+=h0v*w0.w;
      acc1[0][0]+=h1v*w1.x; acc1[0][1]+=h1v*w1.y; acc1[0][2]+=h1v*w1.z; acc1[0][3]+=h1v*w1.w;
    }
  }
  #pragma unroll
  for(int ki=0;ki<4;++ki){
    *(float4*)&Out[(size_t)(n0+q0)*2048 + (k0+ki)*16 + m0] = make_float4(acc0[0][ki],acc0[1][ki],acc0[2][ki],acc0[3][ki]);
    *(float4*)&Out[(size_t)(n0+q1)*2048 + (k0+ki)*16 + m0] = make_float4(acc1[0][ki],acc1[1][ki],acc1[2][ki],acc1[3][ki]);
  }
  if(mode==2 && mg==0){
    const float* W0 = Wsk + (size_t)zs[q0]*16384;
    const float* W1 = Wsk + (size_t)zs[q1]*16384;
    float a0[4]={0,0,0,0}, a1[4]={0,0,0,0};
    for(int s=0;s<KCH;++s){
      float x0v = xs[q0][s*16], x1v = xs[q1][s*16];
      float4 w0 = *(const float4*)&W0[s*128+k0];
      float4 w1 = *(const float4*)&W1[s*128+k0];
      a0[0]+=x0v*w0.x; a0[1]+=x0v*w0.y; a0[2]+=x0v*w0.z; a0[3]+=x0v*w0.w;
      a1[0]+=x1v*w1.x; a1[1]+=x1v*w1.y; a1[2]+=x1v*w1.z; a1[3]+=x1v*w1.w;
    }
    *(float4*)&gh[(size_t)(n0+q0)*KCH + k0] = make_float4(a0[0],a0[1],a0[2],a0[3]);
    *(float4*)&gh[(size_t)(n0+q1)*KCH + k0] = make_float4(a1[0],a1[1],a1[2],a1[3]);
  }
}

// ---------------- unified polynomial contraction: fwd and/or bwd ----------------
// Gtot[x] = C1[x] + (C2S a)[x] + pairsum[x];  B = 2/3 b1 + 1/6 b2 + 1/3 (a.Gtot)
// gA[x] = gB * Gtot[x].   2 items per thread (idx, idx+half), 128-thread blocks.
__global__ __launch_bounds__(128) void k_poly(const float* A, const float* C1, const float* C2S, const float* P,
                                              const int* eptr, const int* eidx,
                                              float* B, float* gA,
                                              const float* gBvec, const float* gBbuf){
  __shared__ float Ps[PSZ];
  __shared__ float C2s_[256];
  __shared__ float C1s_[16];
  int t = threadIdx.x;
  int z = blockIdx.x >> 7, c = blockIdx.x & 127;
  size_t cb = (size_t)z*KCH + c;
  {
    const float4* Pg = (const float4*)(P + cb*PSZ);
    float4* Ps4 = (float4*)Ps;
    for(int i=t;i<PSZ/4;i+=128) Ps4[i] = Pg[i];
    const float4* Cg = (const float4*)(C2S + cb*256);
    float4* Cs4 = (float4*)C2s_;
    if(t<64) Cs4[t] = Cg[t];
    if(t<16) C1s_[t] = C1[cb*16 + t];
  }
  __syncthreads();
  int s0 = eptr[z], cnt = eptr[z+1]-s0;
  int half = (cnt+1)>>1;
  for(int idx=t; idx<half; idx+=128){
    int n0 = eidx[s0+idx];
    bool has1 = (idx+half < cnt);
    int n1 = has1 ? eidx[s0+idx+half] : n0;
    float a0[16], a1[16], G0[16], G1[16];
    {
      const float4* ap = (const float4*)(A + (size_t)n0*2048 + c*16);
      float4 v;
      v=ap[0]; a0[0]=v.x;a0[1]=v.y;a0[2]=v.z;a0[3]=v.w;
      v=ap[1]; a0[4]=v.x;a0[5]=v.y;a0[6]=v.z;a0[7]=v.w;
      v=ap[2]; a0[8]=v.x;a0[9]=v.y;a0[10]=v.z;a0[11]=v.w;
      v=ap[3]; a0[12]=v.x;a0[13]=v.y;a0[14]=v.z;a0[15]=v.w;
      const float4* bp = (const float4*)(A + (size_t)n1*2048 + c*16);
      v=bp[0]; a1[0]=v.x;a1[1]=v.y;a1[2]=v.z;a1[3]=v.w;
      v=bp[1]; a1[4]=v.x;a1[5]=v.y;a1[6]=v.z;a1[7]=v.w;
      v=bp[2]; a1[8]=v.x;a1[9]=v.y;a1[10]=v.z;a1[11]=v.w;
      v=bp[3]; a1[12]=v.x;a1[13]=v.y;a1[14]=v.z;a1[15]=v.w;
    }
    float b1_0=0.f, b1_1=0.f, b2_0=0.f, b2_1=0.f;
    #pragma unroll
    for(int x=0;x<16;++x){
      float cv0=0.f, cv1=0.f;
      #pragma unroll
      for(int b=0;b<16;++b){
        float wv = C2s_[x*16+b];
        cv0 += a0[b]*wv; cv1 += a1[b]*wv;
      }
      float c1v = C1s_[x];
      G0[x] = c1v + cv0;  G1[x] = c1v + cv1;
      b1_0 += a0[x]*c1v;  b1_1 += a1[x]*c1v;
      b2_0 += a0[x]*cv0;  b2_1 += a1[x]*cv1;
    }
    int pair=0;
    #pragma unroll
    for(int j=0;j<16;++j){
      #pragma unroll
      for(int k=j;k<16;++k){
        float pp0 = a0[j]*a0[k];
        float pp1 = a1[j]*a1[k];
        const float4* Pp = (const float4*)&Ps[pair*16];
        #pragma unroll
        for(int q4=0;q4<4;++q4){
          float4 pv = Pp[q4];
          G0[q4*4+0] += pp0*pv.x; G0[q4*4+1] += pp0*pv.y; G0[q4*4+2] += pp0*pv.z; G0[q4*4+3] += pp0*pv.w;
          G1[q4*4+0] += pp1*pv.x; G1[q4*4+1] += pp1*pv.y; G1[q4*4+2] += pp1*pv.z; G1[q4*4+3] += pp1*pv.w;
        }
        ++pair;
      }
    }
    if(B){
      float d0=0.f, d1=0.f;
      #pragma unroll
      for(int x=0;x<16;++x){ d0 += a0[x]*G0[x]; d1 += a1[x]*G1[x]; }
      B[(size_t)n0*KCH + c] = (2.f/3.f)*b1_0 + (1.f/6.f)*b2_0 + (1.f/3.f)*d0;
      if(has1)
        B[(size_t)n1*KCH + c] = (2.f/3.f)*b1_1 + (1.f/6.f)*b2_1 + (1.f/3.f)*d1;
    }
    if(gA){
      float g0 = gBvec ? gBvec[c] : gBbuf[(size_t)n0*KCH + c];
      float* gp0 = gA + (size_t)n0*2048 + c*16;
      #pragma unroll
      for(int x=0;x<16;++x) gp0[x] = g0*G0[x];
      if(has1){
        float g1 = gBvec ? gBvec[c] : gBbuf[(size_t)n1*KCH + c];
        float* gp1 = gA + (size_t)n1*2048 + c*16;
        #pragma unroll
        for(int x=0;x<16;++x) gp1[x] = g1*G1[x];
      }
    }
  }
}

// ---------------- fused edge backward (round-4 proven version) ----------------
__global__ __launch_bounds__(256) void k_edge_bwd2(const float* gagg, const float* hup, const float* w,
                                                   const float* Y, const float* dY,
                                                   const float* vec, const float* rr,
                                                   const float* ef, const float* defdr,
                                                   const float* Wr1, const float* Wr2,
                                                   const float* Wr2T, const float* Wr3T,
                                                   const int* snds, const int* rcvs, int E,
                                                   float* ghup, float* gvec, int do_ghup, int accv){
  __shared__ float Ys[4][16];
  __shared__ float gwS[4][512];
  __shared__ float gYp[4][2][16];
  __shared__ float t1s[4][64];
  __shared__ float gz2s[4][64];
  __shared__ float efS[4][8];
  __shared__ float defS[4][8];
  int t = threadIdx.x;
  int e0 = blockIdx.x*4;
  const float inv16 = 1.f/16.f;
  if(t<64){ int le=t>>4; int ec = e0+le; if(ec<E) Ys[le][t&15] = Y[(size_t)ec*16 + (t&15)]; }
  else if(t<96){ int i=t-64; int le=i>>3; int ec=e0+le; if(ec<E) efS[le][i&7]=ef[(size_t)ec*8+(i&7)]; }
  else if(t<128){ int i=t-96; int le=i>>3; int ec=e0+le; if(ec<E) defS[le][i&7]=defdr[(size_t)ec*8+(i&7)]; }
  __syncthreads();
  for(int rep=0;rep<2;++rep){
    int le = (t>>7) + 2*rep;
    int k = t&127;
    int e = e0+le;
    bool valid = (e<E);
    int eC = valid ? e : (E-1);
    int snd = snds[eC], rcv = rcvs[eC];
    float hv = hup[(size_t)snd*KCH + k];
    float4 w4 = ((const float4*)(w + (size_t)eC*512))[k];
    float g[16];
    const float4* gp = (const float4*)(gagg + (size_t)rcv*2048 + k*16);
    float4 v4;
    v4=gp[0]; g[0]=v4.x;g[1]=v4.y;g[2]=v4.z;g[3]=v4.w;
    v4=gp[1]; g[4]=v4.x;g[5]=v4.y;g[6]=v4.z;g[7]=v4.w;
    v4=gp[2]; g[8]=v4.x;g[9]=v4.y;g[10]=v4.z;g[11]=v4.w;
    v4=gp[3]; g[12]=v4.x;g[13]=v4.y;g[14]=v4.z;g[15]=v4.w;
    const float* Yl = Ys[le];
    float p0 = g[0]*Yl[0];
    float p1 = g[1]*Yl[1]+g[2]*Yl[2]+g[3]*Yl[3];
    float p2 = g[4]*Yl[4]+g[5]*Yl[5]+g[6]*Yl[6]+g[7]*Yl[7]+g[8]*Yl[8];
    float p3 = g[9]*Yl[9]+g[10]*Yl[10]+g[11]*Yl[11]+g[12]*Yl[12]+g[13]*Yl[13]+g[14]*Yl[14]+g[15]*Yl[15];
    float hs = hv*inv16;
    ((float4*)(&gwS[le][k*4]))[0] = make_float4(p0*hs, p1*hs, p2*hs, p3*hs);
    if(do_ghup && valid){
      float s = (p0*w4.x + p1*w4.y + p2*w4.z + p3*w4.w)*inv16;
      atomicAdd(&ghup[(size_t)snd*KCH+k], s);
    }
    float q[16];
    q[0]=g[0]*w4.x*hv;
    q[1]=g[1]*w4.y*hv; q[2]=g[2]*w4.y*hv; q[3]=g[3]*w4.y*hv;
    q[4]=g[4]*w4.z*hv; q[5]=g[5]*w4.z*hv; q[6]=g[6]*w4.z*hv; q[7]=g[7]*w4.z*hv; q[8]=g[8]*w4.z*hv;
    #pragma unroll
    for(int m=9;m<16;++m) q[m]=g[m]*w4.w*hv;
    #pragma unroll
    for(int m=0;m<16;++m){
      float vv=q[m];
      #pragma unroll
      for(int off2=1; off2<64; off2<<=1) vv += __shfl_xor(vv, off2, 64);
      q[m]=vv;
    }
    if((t&63)==0){
      int wv2 = (t>>6)&1;
      #pragma unroll
      for(int m=0;m<16;++m) gYp[le][wv2][m]=q[m];
    }
  }
  __syncthreads();
  {
    int el = t>>6, j = t&63;
    int e = e0+el;
    bool valid = (e<E);
    int eC = valid ? e : (E-1);
    float z1=0;
    #pragma unroll
    for(int b=0;b<8;++b) z1 += efS[el][b]*Wr1[b*64+j];
    float ds1v = dsiluf(z1);
    t1s[el][j] = siluf(z1);
    __syncthreads();
    float z2=0;
    for(int i=0;i<64;++i) z2 += t1s[el][i]*Wr2[i*64+j];
    float ds2v = dsiluf(z2);
    float gt2=0;
    for(int i=0;i<512;++i) gt2 += gwS[el][i]*Wr3T[i*64+j];
    gz2s[el][j] = gt2*ds2v;
    __syncthreads();
    float gz1=0;
    for(int o=0;o<64;++o) gz1 += gz2s[el][o]*Wr2T[o*64+j];
    gz1 *= ds1v;
    float cj=0;
    #pragma unroll
    for(int b=0;b<8;++b) cj += Wr1[b*64+j]*defS[el][b];
    float p = gz1*cj;
    #pragma unroll
    for(int off2=1;off2<64;off2<<=1) p += __shfl_xor(p,off2,64);
    if(j<3 && valid){
      float s = p * vec[(size_t)eC*3+j] / rr[eC];
      #pragma unroll
      for(int m=0;m<16;++m)
        s += (gYp[el][0][m]+gYp[el][1][m])*inv16 * dY[(size_t)eC*48 + m*3 + j];
      if(accv) gvec[(size_t)eC*3+j] += s;
      else     gvec[(size_t)eC*3+j]  = s;
    }
  }
}

// ---------------- energy readout ----------------
__global__ void k_energy(const float* h2, const float* Wro, const float* AE,
                         const int* elem, const int* batch, float* out, int N){
  int n = blockIdx.x*256 + threadIdx.x;
  if(n>=N) return;
  float s=0;
  for(int k=0;k<KCH;++k) s += h2[(size_t)n*KCH+k]*Wro[k];
  s += AE[elem[n]];
  atomicAdd(&out[batch[n]], s);
}

// ---------------- forces scatter ----------------
__global__ void k_forces(const float* gvec, const int* snds, const int* rcvs, int E, float* fout){
  int i = blockIdx.x*256 + threadIdx.x;
  if(i>=E*3) return;
  int e = i/3, j = i - e*3;
  float g = gvec[i];
  atomicAdd(&fout[(size_t)snds[e]*3+j], g);
  atomicAdd(&fout[(size_t)rcvs[e]*3+j], -g);
}

// =============================================================
extern "C" void kernel_launch(void* const* d_in, const int* in_sizes, int n_in,
                              void* d_out, int out_size, void* d_ws, size_t ws_size,
                              hipStream_t stream){
  const float* attrs  = (const float*)d_in[0];
  const float* pos    = (const float*)d_in[1];
  const float* shifts = (const float*)d_in[2];
  const float* AE     = (const float*)d_in[3];
  const float* Wemb   = (const float*)d_in[4];
  const float* Wup    = (const float*)d_in[5];
  const float* Wr1    = (const float*)d_in[6];
  const float* Wr2    = (const float*)d_in[7];
  const float* Wr3    = (const float*)d_in[8];
  const float* Wlin   = (const float*)d_in[9];
  const float* Wskip  = (const float*)d_in[10];
  const float* U1     = (const float*)d_in[11];
  const float* U2     = (const float*)d_in[12];
  const float* U3     = (const float*)d_in[13];
  const float* Wc1    = (const float*)d_in[14];
  const float* Wc2    = (const float*)d_in[15];
  const float* Wc3    = (const float*)d_in[16];
  const float* Wprod  = (const float*)d_in[17];
  const float* Wro    = (const float*)d_in[18];
  const int*   ei     = (const int*)d_in[19];
  const int*   batch  = (const int*)d_in[20];
  int N = in_sizes[1]/3;
  int E = in_sizes[19]/2;
  float* out = (float*)d_out;
  int G = out_size - 3*N;

  char* base = (char*)d_ws;
  size_t off = 0;
  auto alloc = [&](size_t nbytes)->void*{
    void* p = base + off;
    off += (nbytes + 255) & ~(size_t)255;
    return p;
  };
  int* elem = (int*)alloc((size_t)N*4);
  int* rptr = (int*)alloc((size_t)(N+1)*4);
  // zeroed counter block (contiguous)
  int* rcnt = (int*)alloc((size_t)N*4);
  int* rcur = (int*)alloc((size_t)N*4);
  int* ecnt = (int*)alloc((size_t)NELEM*4);
  int* ecur = (int*)alloc((size_t)NELEM*4);
  size_t zspan = (size_t)((base+off) - (char*)rcnt) / 4;
  int* ridx = (int*)alloc((size_t)E*4);
  int* eptr = (int*)alloc((size_t)(NELEM+1)*4);
  int* eidx = (int*)alloc((size_t)N*4);
  int* snds = (int*)alloc((size_t)E*4);
  int* rcvs = (int*)alloc((size_t)E*4);
  float* h0   = (float*)alloc((size_t)N*KCH*4);
  float* h1   = (float*)alloc((size_t)N*KCH*4);
  float* h2   = (float*)alloc((size_t)N*KCH*4);
  float* hup0 = (float*)alloc((size_t)N*KCH*4);
  float* hup1 = (float*)alloc((size_t)N*KCH*4);
  float* vecb = (float*)alloc((size_t)E*3*4);
  float* rb   = (float*)alloc((size_t)E*4);
  float* Yb   = (float*)alloc((size_t)E*16*4);
  float* dYb  = (float*)alloc((size_t)E*48*4);
  float* efb  = (float*)alloc((size_t)E*8*4);
  float* defb = (float*)alloc((size_t)E*8*4);
  float* wb   = (float*)alloc((size_t)E*512*4);
  float* A0   = (float*)alloc((size_t)N*2048*4);
  float* A1   = (float*)alloc((size_t)N*2048*4);
  float* aggb = (float*)alloc((size_t)N*2048*4);
  float* gAb  = (float*)alloc((size_t)N*2048*4);
  float* Bbuf = (float*)alloc((size_t)N*KCH*4);
  float* gh1  = (float*)alloc((size_t)N*KCH*4);
  float* ghup = (float*)alloc((size_t)N*KCH*4);
  float* gB0b = (float*)alloc((size_t)N*KCH*4);
  float* gB1v = (float*)alloc((size_t)KCH*4);
  float* gvecb= (float*)alloc((size_t)E*3*4);
  float* C1b  = (float*)alloc((size_t)NELEM*KCH*16*4);
  float* C2Sb = (float*)alloc((size_t)NELEM*KCH*256*4);
  float* Pb   = (float*)alloc((size_t)NELEM*KCH*PSZ*4);
  float* U2s  = (float*)alloc(1024*4);
  float* U3s  = (float*)alloc(32768*4);
  float* WupT1   = (float*)alloc(16384*4);
  float* WprodT0 = (float*)alloc(16384*4);
  float* WskipT1 = (float*)alloc((size_t)NELEM*16384*4);
  float* Wbig0  = (float*)alloc((size_t)16*16384*4);
  float* Wbig1  = (float*)alloc((size_t)16*16384*4);
  float* WbigT0 = (float*)alloc((size_t)16*16384*4);
  float* WbigT1 = (float*)alloc((size_t)16*16384*4);
  float* Wr3T0   = (float*)alloc(32768*4);
  float* Wr3T1   = (float*)alloc(32768*4);
  float* Wr2T0   = (float*)alloc(4096*4);
  float* Wr2T1   = (float*)alloc(4096*4);
  if(off > ws_size) return; // insufficient workspace

  // PRIORITY 1: second C-tensor set (layer-1) — enables fused layer-1 fwd+bwd poly
  float *C1_1=C1b, *C2_1=C2Sb, *P_1=Pb; int have_c2 = 0;
  {
    size_t need = ((size_t)NELEM*KCH*16 + (size_t)NELEM*KCH*256 + (size_t)NELEM*KCH*PSZ)*4 + 1024;
    if(off + need <= ws_size){
      C1_1 = (float*)alloc((size_t)NELEM*KCH*16*4);
      C2_1 = (float*)alloc((size_t)NELEM*KCH*256*4);
      P_1  = (float*)alloc((size_t)NELEM*KCH*PSZ*4);
      have_c2 = 1;
    }
  }
  // PRIORITY 2: second w buffer (layer-1 w)
  float* wb1 = wb; int have_wb1 = 0;
  if(off + (size_t)E*512*4 <= ws_size){ wb1 = (float*)alloc((size_t)E*512*4); have_wb1 = 1; }

  const int KK = KCH*KCH;           // 16384
  dim3 b256(256), b128(128);
  #define GR(n) dim3(((n)+255)/256)

  // zeros (counters fused; out; ghup)
  k_zero<<<GR(out_size),b256,0,stream>>>(out, out_size);
  k_zero<<<GR((int)zspan),b256,0,stream>>>((float*)rcnt, (int)zspan);
  k_zero<<<GR(N*KCH),b256,0,stream>>>(ghup, N*KCH);

  // elem + embed
  k_elem<<<GR(N),b256,0,stream>>>(attrs, elem, N);
  k_h0<<<GR(N*KCH),b256,0,stream>>>(Wemb, elem, h0, N);

  // CSR by recv
  k_hist<<<GR(E),b256,0,stream>>>(ei+E, rcnt, E);
  k_scan<<<1,b256,0,stream>>>(rcnt, rptr, N);
  k_scatter<<<GR(E),b256,0,stream>>>(ei+E, rptr, rcur, ridx, E);
  // node lists by element
  k_hist<<<GR(N),b256,0,stream>>>(elem, ecnt, N);
  k_scan<<<1,b256,0,stream>>>(ecnt, eptr, NELEM);
  k_scatter<<<GR(N),b256,0,stream>>>(elem, eptr, ecur, eidx, N);

  // fused weight prep
  k_prep<<<GR(PREP_ITEMS),b256,0,stream>>>(Wup, Wprod, Wskip, Wlin, Wr2, Wr3, U2, U3,
                                           WupT1, WprodT0, WskipT1,
                                           Wbig0, Wbig1, WbigT0, WbigT1,
                                           Wr3T0, Wr3T1, Wr2T0, Wr2T1, U2s, U3s);
  k_gB1<<<1,b128,0,stream>>>(Wro, Wprod + KK, gB1v);

  // edge geometry (sorted order)
  k_edge_geom<<<GR(E),b256,0,stream>>>(pos, shifts, ei, ridx, E, snds, rcvs,
                                       vecb, rb, Yb, dYb, efb, defb);

  dim3 mmG((N+7)/8);
  dim3 mxG((N+3)/4);
  dim3 polyG(NELEM*KCH);
  dim3 rwG((E+15)/16);
  dim3 ebG((E+3)/4);

  // ---------- layer 0 forward ----------
  k_ctens<<<GR(CTENS_ITEMS),b256,0,stream>>>(U1, U2s, U3s, Wc1, Wc2, Wc3, C1b, C2Sb, Pb);
  k_mm<<<mmG,b128,0,stream>>>(h0, Wup, hup0, N, 0);
  k_radial_w<<<rwG,b256,0,stream>>>(efb, Wr1, Wr2, Wr3, wb, E);
  k_gather<<<dim3(N),b256,0,stream>>>(hup0, wb, Yb, rptr, snds, aggb, E);
  k_mixed2<<<mxG,b256,0,stream>>>(aggb, h0, elem, Wbig0, Wskip, A0, nullptr, N, 0);
  k_poly<<<polyG,b128,0,stream>>>(A0, C1b, C2Sb, Pb, eptr, eidx, Bbuf, nullptr, nullptr, nullptr);
  k_mm<<<mmG,b128,0,stream>>>(Bbuf, Wprod, h1, N, 0);

  // ---------- layer 1 forward (poly also emits gA1 since gB1 is data-independent) ----------
  k_ctens<<<GR(CTENS_ITEMS),b256,0,stream>>>(U1, U2s, U3s,
                                             Wc1 + NELEM*2*KCH, Wc2 + NELEM*4*KCH, Wc3 + NELEM*8*KCH,
                                             C1_1, C2_1, P_1);
  k_mm<<<mmG,b128,0,stream>>>(h1, Wup + KK, hup1, N, 0);
  k_radial_w<<<rwG,b256,0,stream>>>(efb, Wr1 + 512, Wr2 + 4096, Wr3 + 32768, wb1, E);
  k_gather<<<dim3(N),b256,0,stream>>>(hup1, wb1, Yb, rptr, snds, aggb, E);
  k_mixed2<<<mxG,b256,0,stream>>>(aggb, h1, elem, Wbig1, Wskip + (size_t)NELEM*KK, A1, nullptr, N, 0);
  k_poly<<<polyG,b128,0,stream>>>(A1, C1_1, C2_1, P_1, eptr, eidx, Bbuf, gAb, gB1v, nullptr);
  k_mm<<<mmG,b128,0,stream>>>(Bbuf, Wprod + KK, h2, N, 0);

  // energy
  k_energy<<<GR(N),b256,0,stream>>>(h2, Wro, AE, elem, batch, out, N);

  // ---------- layer 1 backward (gAb already computed) ----------
  k_mixed2<<<mxG,b256,0,stream>>>(gAb, nullptr, elem, WbigT1, WskipT1, aggb, gh1, N, 2);
  k_edge_bwd2<<<ebG,b256,0,stream>>>(aggb, hup1, wb1, Yb, dYb, vecb, rb, efb, defb,
                                     Wr1 + 512, Wr2 + 4096, Wr2T1, Wr3T1, snds, rcvs, E,
                                     ghup, gvecb, 1, 0);
  k_mm<<<mmG,b128,0,stream>>>(ghup, WupT1, gh1, N, 1);

  // ---------- layer 0 backward ----------
  if(!have_c2)
    k_ctens<<<GR(CTENS_ITEMS),b256,0,stream>>>(U1, U2s, U3s, Wc1, Wc2, Wc3, C1b, C2Sb, Pb);
  k_mm<<<mmG,b128,0,stream>>>(gh1, WprodT0, gB0b, N, 0);
  k_poly<<<polyG,b128,0,stream>>>(A0, C1b, C2Sb, Pb, eptr, eidx, nullptr, gAb, nullptr, gB0b);
  k_mixed2<<<mxG,b256,0,stream>>>(gAb, nullptr, elem, WbigT0, nullptr, aggb, nullptr, N, 1);
  if(!have_wb1)
    k_radial_w<<<rwG,b256,0,stream>>>(efb, Wr1, Wr2, Wr3, wb, E);
  k_edge_bwd2<<<ebG,b256,0,stream>>>(aggb, hup0, wb, Yb, dYb, vecb, rb, efb, defb,
                                     Wr1, Wr2, Wr2T0, Wr3T0, snds, rcvs, E,
                                     ghup, gvecb, 0, 1);

  // forces
  k_forces<<<GR(E*3),b256,0,stream>>>(gvecb, snds, rcvs, E, out + G);
  #undef GR
}

// Round 9
// 1630.044 us; speedup vs baseline: 1.5087x; 1.0534x over previous
//
#include <hip/hip_runtime.h>
#include <math.h>

#define KCH 128
#define NELEM 10
#define NPAIR 136   // 16*17/2
#define PSZ   2176  // NPAIR*16

__device__ __forceinline__ int lidxf(int m){ return (m==0)?0:((m<4)?1:((m<9)?2:3)); }
__device__ __forceinline__ float siluf(float z){ return z/(1.f+expf(-z)); }
__device__ __forceinline__ float dsiluf(float z){ float s=1.f/(1.f+expf(-z)); return s*(1.f+z*(1.f-s)); }

// ---------------- utility ----------------
__global__ void k_zero(float* p, int n){
  int i = blockIdx.x*256 + threadIdx.x;
  if(i<n) p[i]=0.f;
}

__global__ void k_elem(const float* attrs, int* elem, int N){
  int n = blockIdx.x*256 + threadIdx.x;
  if(n>=N) return;
  int z=0;
  for(int e=0;e<NELEM;++e) if(attrs[n*NELEM+e] > 0.5f) z=e;
  elem[n]=z;
}

__global__ void k_h0(const float* Wemb, const int* elem, float* h0, int N){
  int i = blockIdx.x*256 + threadIdx.x;
  if(i>=N*KCH) return;
  int n = i>>7, k = i&127;
  h0[i] = Wemb[elem[n]*KCH + k];
}

__global__ void k_hist(const int* keys, int* cnt, int n){
  int i = blockIdx.x*256 + threadIdx.x;
  if(i<n) atomicAdd(&cnt[keys[i]],1);
}

__global__ void k_scan(const int* cnt, int* ptr, int n){
  __shared__ int part[257];
  int t = threadIdx.x;
  int csz = (n+255)/256;
  int lo = t*csz, hi = (t+1)*csz; if(hi>n) hi=n;
  int s=0;
  for(int i=lo;i<hi;++i) s+=cnt[i];
  part[t]=s; __syncthreads();
  if(t==0){ int acc=0; for(int i=0;i<256;++i){ int v=part[i]; part[i]=acc; acc+=v; } part[256]=acc; }
  __syncthreads();
  int acc = part[t];
  for(int i=lo;i<hi;++i){ ptr[i]=acc; acc+=cnt[i]; }
  if(t==255) ptr[n]=part[256];
}

__global__ void k_scatter(const int* keys, const int* ptr, int* cur, int* idx, int n){
  int i = blockIdx.x*256 + threadIdx.x;
  if(i>=n) return;
  int k = keys[i];
  int p = atomicAdd(&cur[k],1);
  idx[ptr[k]+p] = i;
}

// ---------------- fused weight prep ----------------
__global__ void k_prep(const float* Wup, const float* Wprod, const float* Wskip, const float* Wlin,
                       const float* Wr2, const float* Wr3, const float* U2, const float* U3,
                       float* WupT1, float* WprodT0, float* WskipT1,
                       float* Wbig0, float* Wbig1, float* WbigT0, float* WbigT1,
                       float* Wr3T0, float* Wr3T1, float* Wr2T0, float* Wr2T1,
                       float* U2s, float* U3s){
  int i = blockIdx.x*256 + threadIdx.x;
  const int KK = 16384;
  if(i < KK){ int r=i>>7, c=i&127; WupT1[c*128+r] = Wup[KK + i]; return; }
  i -= KK;
  if(i < KK){ int r=i>>7, c=i&127; WprodT0[c*128+r] = Wprod[i]; return; }
  i -= KK;
  if(i < NELEM*KK){ int mat=i>>14, rc=i&16383, r=rc>>7, c=rc&127;
    WskipT1[mat*KK + c*128 + r] = Wskip[(size_t)NELEM*KK + i]; return; }
  i -= NELEM*KK;
  if(i < 16*KK){ int m=i>>14, sk=i&16383; Wbig0[i] = Wlin[lidxf(m)*KK + sk]; return; }
  i -= 16*KK;
  if(i < 16*KK){ int m=i>>14, sk=i&16383; Wbig1[i] = Wlin[4*KK + lidxf(m)*KK + sk]; return; }
  i -= 16*KK;
  if(i < 16*KK){ int m=i>>14, sk=i&16383, s=sk>>7, k=sk&127; WbigT0[i] = Wlin[lidxf(m)*KK + k*128 + s]; return; }
  i -= 16*KK;
  if(i < 16*KK){ int m=i>>14, sk=i&16383, s=sk>>7, k=sk&127; WbigT1[i] = Wlin[4*KK + lidxf(m)*KK + k*128 + s]; return; }
  i -= 16*KK;
  if(i < 32768){ int r=i>>9, c=i&511; Wr3T0[c*64+r] = Wr3[i]; return; }
  i -= 32768;
  if(i < 32768){ int r=i>>9, c=i&511; Wr3T1[c*64+r] = Wr3[32768 + i]; return; }
  i -= 32768;
  if(i < 4096){ int r=i>>6, c=i&63; Wr2T0[c*64+r] = Wr2[i]; return; }
  i -= 4096;
  if(i < 4096){ int r=i>>6, c=i&63; Wr2T1[c*64+r] = Wr2[4096 + i]; return; }
  i -= 4096;
  if(i < 1024){ int p=i&3, b=(i>>2)&15, a=(i>>6)&15;
    U2s[i] = U2[a*64+b*4+p] + U2[b*64+a*4+p]; return; }
  i -= 1024;
  if(i < 32768){
    int p=i&7, c=(i>>3)&15, b=(i>>7)&15, a=(i>>11)&15;
    U3s[i] = U3[a*2048+b*128+c*8+p] + U3[a*2048+c*128+b*8+p]
           + U3[b*2048+a*128+c*8+p] + U3[b*2048+c*128+a*8+p]
           + U3[c*2048+a*128+b*8+p] + U3[c*2048+b*128+a*8+p];
    return;
  }
}
#define PREP_ITEMS (16384*76 + 32768*2 + 4096*2 + 1024 + 32768)

// ---------------- fused contracted tensors (per layer) ----------------
__global__ void k_ctens(const float* U1, const float* U2s, const float* U3s,
                        const float* Wc1l, const float* Wc2l, const float* Wc3l,
                        float* C1, float* C2S, float* P){
  int i = blockIdx.x*256 + threadIdx.x;
  if(i < NELEM*KCH*16){
    int a=i&15, c=(i>>4)&127, z=i>>11;
    float s=0;
    for(int p=0;p<2;++p) s += U1[a*2+p]*Wc1l[z*2*KCH + p*KCH + c];
    C1[i]=s; return;
  }
  i -= NELEM*KCH*16;
  if(i < NELEM*KCH*256){
    int ab=i&255, c=(i>>8)&127, z=i>>15;
    float s=0;
    for(int p=0;p<4;++p) s += U2s[ab*4+p]*Wc2l[z*4*KCH + p*KCH + c];
    C2S[i]=s; return;
  }
  i -= NELEM*KCH*256;
  if(i < NELEM*KCH*PSZ){
    int x = i & 15;
    int t2 = i >> 4;
    int pair = t2 % NPAIR;
    int cz = t2 / NPAIR;
    int c = cz & 127, z = cz >> 7;
    int j=0, rem=pair;
    while(rem >= 16-j){ rem -= 16-j; ++j; }
    int k = j + rem;
    const float* u = U3s + (size_t)j*2048 + k*128 + x*8;
    float s=0;
    #pragma unroll
    for(int p=0;p<8;++p) s += u[p]*Wc3l[z*8*KCH + p*KCH + c];
    if(j==k) s *= 0.5f;
    P[i] = s; return;
  }
}
#define CTENS_ITEMS (NELEM*KCH*16 + NELEM*KCH*256 + NELEM*KCH*PSZ)

__global__ void k_gB1(const float* Wro, const float* Wprod1, float* gB1){
  int c = threadIdx.x;
  float s=0;
  for(int h=0;h<KCH;++h) s += Wro[h]*Wprod1[c*KCH+h];
  gB1[c]=s;
}

// ---------------- edge geometry (writes in recv-sorted order) ----------------
__global__ void k_edge_geom(const float* pos, const float* shifts, const int* ei, const int* ridx, int E,
                            int* snds, int* rcvs,
                            float* vec, float* rr, float* Y, float* dY, float* ef, float* defdr){
  int i = blockIdx.x*256 + threadIdx.x;
  if(i>=E) return;
  int e = ridx[i];
  int s = ei[e], rc = ei[E+e];
  snds[i]=s; rcvs[i]=rc;
  float vx = pos[rc*3+0]-pos[s*3+0]+shifts[e*3+0];
  float vy = pos[rc*3+1]-pos[s*3+1]+shifts[e*3+1];
  float vz = pos[rc*3+2]-pos[s*3+2]+shifts[e*3+2];
  float r2 = vx*vx+vy*vy+vz*vz + 1e-12f;
  float n = sqrtf(r2);
  float inv_n = 1.f/n;
  float x = vx*inv_n, y = vy*inv_n, z = vz*inv_n;
  vec[i*3+0]=vx; vec[i*3+1]=vy; vec[i*3+2]=vz; rr[i]=n;
  const float s3=1.7320508075688772f, s15=3.8729833462074170f, s5=2.2360679774997896f;
  const float s70=8.3666002653407556f, s105=10.2469507659595980f, s42=6.4807406984078604f, s7=2.6457513110645907f;
  float Yv[16], d0[16], d1[16], d2[16];
  Yv[0]=1.f; d0[0]=0;d1[0]=0;d2[0]=0;
  Yv[1]=s3*x; d0[1]=s3; d1[1]=0; d2[1]=0;
  Yv[2]=s3*y; d0[2]=0; d1[2]=s3; d2[2]=0;
  Yv[3]=s3*z; d0[3]=0; d1[3]=0; d2[3]=s3;
  Yv[4]=s15*x*y; d0[4]=s15*y; d1[4]=s15*x; d2[4]=0;
  Yv[5]=s15*y*z; d0[5]=0; d1[5]=s15*z; d2[5]=s15*y;
  Yv[6]=0.5f*s5*(3.f*z*z-1.f); d0[6]=0; d1[6]=0; d2[6]=3.f*s5*z;
  Yv[7]=s15*x*z; d0[7]=s15*z; d1[7]=0; d2[7]=s15*x;
  Yv[8]=0.5f*s15*(x*x-y*y); d0[8]=s15*x; d1[8]=-s15*y; d2[8]=0;
  Yv[9]=0.25f*s70*y*(3.f*x*x-y*y); d0[9]=1.5f*s70*x*y; d1[9]=0.75f*s70*(x*x-y*y); d2[9]=0;
  Yv[10]=s105*x*y*z; d0[10]=s105*y*z; d1[10]=s105*x*z; d2[10]=s105*x*y;
  Yv[11]=0.25f*s42*y*(5.f*z*z-1.f); d0[11]=0; d1[11]=0.25f*s42*(5.f*z*z-1.f); d2[11]=2.5f*s42*y*z;
  Yv[12]=0.5f*s7*z*(5.f*z*z-3.f); d0[12]=0; d1[12]=0; d2[12]=0.5f*s7*(15.f*z*z-3.f);
  Yv[13]=0.25f*s42*x*(5.f*z*z-1.f); d0[13]=0.25f*s42*(5.f*z*z-1.f); d1[13]=0; d2[13]=2.5f*s42*x*z;
  Yv[14]=0.5f*s105*z*(x*x-y*y); d0[14]=s105*x*z; d1[14]=-s105*y*z; d2[14]=0.5f*s105*(x*x-y*y);
  Yv[15]=0.25f*s70*x*(3.f*x*x-y*y); d0[15]=0.25f*s70*(9.f*x*x-y*y); d1[15]=-0.5f*s70*x*y; d2[15]=0;
  #pragma unroll
  for(int m=0;m<16;++m){
    float dm = d0[m]*x + d1[m]*y + d2[m]*z;
    dY[(size_t)i*48 + m*3 + 0] = (d0[m]-dm*x)*inv_n;
    dY[(size_t)i*48 + m*3 + 1] = (d1[m]-dm*y)*inv_n;
    dY[(size_t)i*48 + m*3 + 2] = (d2[m]-dm*z)*inv_n;
    Y[(size_t)i*16+m] = Yv[m];
  }
  const float c0 = 0.63245553203367587f; // sqrt(2/5)
  float rp = n + 1e-9f;
  float u = n*0.2f;
  float f, dfdr;
  if(u < 1.f){
    float u2=u*u, u4=u2*u2, u5=u4*u, u6=u5*u, u7=u6*u;
    f = 1.f - 21.f*u5 + 35.f*u6 - 15.f*u7;
    float dfdu = -105.f*u4 + 210.f*u5 - 105.f*u6;
    dfdr = dfdu*0.2f;
  } else { f=0.f; dfdr=0.f; }
  for(int b=0;b<8;++b){
    float kn = (float)(b+1)*0.62831853071795865f; // pi/5
    float sr = sinf(kn*n), cr = cosf(kn*n);
    float bess = c0*sr/rp;
    float dbess = c0*(kn*cr/rp - sr/(rp*rp));
    ef[(size_t)i*8+b] = bess*f;
    defdr[(size_t)i*8+b] = dbess*f + bess*dfdr;
  }
}

// ---------------- small row-block matmul ----------------
__global__ __launch_bounds__(128) void k_mm(const float* X, const float* W, float* Out, int N, int acc){
  __shared__ float xs[8][KCH];
  int t = threadIdx.x;
  int n0 = blockIdx.x*8;
  for(int j=0;j<8;++j){ int n=n0+j; xs[j][t] = (n<N)? X[(size_t)n*KCH+t] : 0.f; }
  __syncthreads();
  float a[8] = {0,0,0,0,0,0,0,0};
  for(int s=0;s<KCH;++s){
    float wv = W[s*KCH + t];
    #pragma unroll
    for(int j=0;j<8;++j) a[j] += xs[j][s]*wv;
  }
  for(int j=0;j<8;++j){
    int n=n0+j;
    if(n<N){ if(acc) Out[(size_t)n*KCH+t] += a[j]; else Out[(size_t)n*KCH+t] = a[j]; }
  }
}

// ---------------- radial MLP -> w (E x 512, sorted order) ----------------
__global__ __launch_bounds__(256) void k_radial_w(const float* ef, const float* Wr1, const float* Wr2, const float* Wr3,
                                                  float* w, int E){
  __shared__ float t1s[16][64];
  __shared__ float t2s[16][64];
  int t = threadIdx.x;
  int e0 = blockIdx.x*16;
  for(int it=0; it<4; ++it){
    int item = t + it*256;
    int el = item>>6, j = item&63;
    float z=0;
    if(e0+el < E){
      const float* efe = ef + (size_t)(e0+el)*8;
      #pragma unroll
      for(int b=0;b<8;++b) z += efe[b]*Wr1[b*64+j];
    }
    t1s[el][j] = siluf(z);
  }
  __syncthreads();
  for(int it=0; it<4; ++it){
    int item = t + it*256;
    int el = item>>6, j = item&63;
    float z=0;
    #pragma unroll
    for(int i=0;i<64;++i) z += t1s[el][i]*Wr2[i*64+j];
    t2s[el][j] = siluf(z);
  }
  __syncthreads();
  float a0[16], a1[16];
  #pragma unroll
  for(int el=0;el<16;++el){ a0[el]=0.f; a1[el]=0.f; }
  for(int j=0;j<64;++j){
    float wa = Wr3[j*512 + t];
    float wb = Wr3[j*512 + t + 256];
    #pragma unroll
    for(int el=0;el<16;++el){
      float tv = t2s[el][j];
      a0[el] += tv*wa;
      a1[el] += tv*wb;
    }
  }
  for(int el=0;el<16;++el){
    if(e0+el < E){
      w[(size_t)(e0+el)*512 + t] = a0[el];
      w[(size_t)(e0+el)*512 + t + 256] = a1[el];
    }
  }
}

// ---------------- message aggregation (2-edge unrolled, float4 Y loads) ----------------
__global__ __launch_bounds__(256) void k_gather(const float* hup, const float* w, const float* Y,
                                                const int* rptr, const int* snds,
                                                float* agg, int E){
  int n = blockIdx.x;
  int t = threadIdx.x;
  int k = t & 127, mg = t >> 7;
  float acc[8] = {0,0,0,0,0,0,0,0};
  int s0 = rptr[n], s1 = rptr[n+1];
  int i = s0;
  for(; i+1<s1; i+=2){
    int snd0 = snds[i], snd1 = snds[i+1];
    float hv0 = hup[(size_t)snd0*KCH + k];
    float hv1 = hup[(size_t)snd1*KCH + k];
    float4 w40 = ((const float4*)(w + (size_t)i*512))[k];
    float4 w41 = ((const float4*)(w + (size_t)(i+1)*512))[k];
    const float4* Yp0 = (const float4*)(Y + (size_t)i*16) + mg*2;
    const float4* Yp1 = (const float4*)(Y + (size_t)(i+1)*16) + mg*2;
    float4 ya0 = Yp0[0], yb0 = Yp0[1];
    float4 ya1 = Yp1[0], yb1 = Yp1[1];
    if(mg==0){
      acc[0] += w40.x*hv0*ya0.x + w41.x*hv1*ya1.x;
      acc[1] += w40.y*hv0*ya0.y + w41.y*hv1*ya1.y;
      acc[2] += w40.y*hv0*ya0.z + w41.y*hv1*ya1.z;
      acc[3] += w40.y*hv0*ya0.w + w41.y*hv1*ya1.w;
      acc[4] += w40.z*hv0*yb0.x + w41.z*hv1*yb1.x;
      acc[5] += w40.z*hv0*yb0.y + w41.z*hv1*yb1.y;
      acc[6] += w40.z*hv0*yb0.z + w41.z*hv1*yb1.z;
      acc[7] += w40.z*hv0*yb0.w + w41.z*hv1*yb1.w;
    } else {
      acc[0] += w40.z*hv0*ya0.x + w41.z*hv1*ya1.x;
      acc[1] += w40.w*hv0*ya0.y + w41.w*hv1*ya1.y;
      acc[2] += w40.w*hv0*ya0.z + w41.w*hv1*ya1.z;
      acc[3] += w40.w*hv0*ya0.w + w41.w*hv1*ya1.w;
      acc[4] += w40.w*hv0*yb0.x + w41.w*hv1*yb1.x;
      acc[5] += w40.w*hv0*yb0.y + w41.w*hv1*yb1.y;
      acc[6] += w40.w*hv0*yb0.z + w41.w*hv1*yb1.z;
      acc[7] += w40.w*hv0*yb0.w + w41.w*hv1*yb1.w;
    }
  }
  if(i<s1){
    int snd0 = snds[i];
    float hv0 = hup[(size_t)snd0*KCH + k];
    float4 w40 = ((const float4*)(w + (size_t)i*512))[k];
    const float4* Yp0 = (const float4*)(Y + (size_t)i*16) + mg*2;
    float4 ya0 = Yp0[0], yb0 = Yp0[1];
    if(mg==0){
      acc[0] += w40.x*hv0*ya0.x;
      acc[1] += w40.y*hv0*ya0.y;
      acc[2] += w40.y*hv0*ya0.z;
      acc[3] += w40.y*hv0*ya0.w;
      acc[4] += w40.z*hv0*yb0.x;
      acc[5] += w40.z*hv0*yb0.y;
      acc[6] += w40.z*hv0*yb0.z;
      acc[7] += w40.z*hv0*yb0.w;
    } else {
      acc[0] += w40.z*hv0*ya0.x;
      acc[1] += w40.w*hv0*ya0.y;
      acc[2] += w40.w*hv0*ya0.z;
      acc[3] += w40.w*hv0*ya0.w;
      acc[4] += w40.w*hv0*yb0.x;
      acc[5] += w40.w*hv0*yb0.y;
      acc[6] += w40.w*hv0*yb0.z;
      acc[7] += w40.w*hv0*yb0.w;
    }
  }
  const float inv = 1.f/16.f;
  float* ap = agg + (size_t)n*2048 + k*16 + mg*8;
  #pragma unroll
  for(int j=0;j<8;++j) ap[j] = acc[j]*inv;
}

// ---------------- mixed (all 16 m per block) + skip / skipT ----------------
__global__ __launch_bounds__(256) void k_mixed2(const float* X, const float* hin, const int* elem,
                                                const float* Wb, const float* Wsk,
                                                float* Out, float* gh, int N, int mode){
  __shared__ float xs[4][2048];
  __shared__ float hs[4][128];
  __shared__ int zs[4];
  int t = threadIdx.x;
  int n0 = blockIdx.x*4;
  for(int q=0;q<4;++q){
    const float4* Xp = (const float4*)(X + (size_t)(n0+q)*2048);
    float4* Xs = (float4*)xs[q];
    Xs[t] = Xp[t]; Xs[t+256] = Xp[t+256];
  }
  if(mode==0 && t<128){
    for(int q=0;q<4;++q) hs[q][t] = hin[(size_t)(n0+q)*KCH + t];
  }
  if(t<4) zs[t]=elem[n0+t];
  __syncthreads();
  int kg = t&31, mg=(t>>5)&3, half=t>>7;
  int k0 = kg*4, m0 = mg*4;
  int q0 = half*2, q1=q0+1;
  float acc0[4][4], acc1[4][4];
  #pragma unroll
  for(int a=0;a<4;++a){
    #pragma unroll
    for(int b=0;b<4;++b){acc0[a][b]=0.f;acc1[a][b]=0.f;}
  }
  for(int s=0;s<KCH;++s){
    float4 x0 = *(const float4*)&xs[q0][s*16+m0];
    float4 x1 = *(const float4*)&xs[q1][s*16+m0];
    #pragma unroll
    for(int mj=0;mj<4;++mj){
      const float4 wv = *(const float4*)&Wb[(size_t)(m0+mj)*16384 + s*128 + k0];
      float xm0 = (mj==0)?x0.x:((mj==1)?x0.y:((mj==2)?x0.z:x0.w));
      float xm1 = (mj==0)?x1.x:((mj==1)?x1.y:((mj==2)?x1.z:x1.w));
      acc0[mj][0]+=xm0*wv.x; acc0[mj][1]+=xm0*wv.y; acc0[mj][2]+=xm0*wv.z; acc0[mj][3]+=xm0*wv.w;
      acc1[mj][0]+=xm1*wv.x; acc1[mj][1]+=xm1*wv.y; acc1[mj][2]+=xm1*wv.z; acc1[mj][3]+=xm1*wv.w;
    }
  }
  if(mode==0 && mg==0){
    const float* W0 = Wsk + (size_t)zs[q0]*16384;
    const float* W1 = Wsk + (size_t)zs[q1]*16384;
    for(int s=0;s<KCH;++s){
      float h0v=hs[q0][s], h1v=hs[q1][s];
      float4 w0 = *(const float4*)&W0[s*128+k0];
      float4 w1 = *(const float4*)&W1[s*128+k0];
      acc0[0][0]+=h0v*w0.x; acc0[0][1]+=h0v*w0.y; acc0[0][2]+=h0v*w0.z; acc0[0][3]+=h0v*w0.w;
      acc1[0][0]+=h1v*w1.x; acc1[0][1]+=h1v*w1.y; acc1[0][2]+=h1v*w1.z; acc1[0][3]+=h1v*w1.w;
    }
  }
  #pragma unroll
  for(int ki=0;ki<4;++ki){
    *(float4*)&Out[(size_t)(n0+q0)*2048 + (k0+ki)*16 + m0] = make_float4(acc0[0][ki],acc0[1][ki],acc0[2][ki],acc0[3][ki]);
    *(float4*)&Out[(size_t)(n0+q1)*2048 + (k0+ki)*16 + m0] = make_float4(acc1[0][ki],acc1[1][ki],acc1[2][ki],acc1[3][ki]);
  }
  if(mode==2 && mg==0){
    const float* W0 = Wsk + (size_t)zs[q0]*16384;
    const float* W1 = Wsk + (size_t)zs[q1]*16384;
    float a0[4]={0,0,0,0}, a1[4]={0,0,0,0};
    for(int s=0;s<KCH;++s){
      float x0v = xs[q0][s*16], x1v = xs[q1][s*16];
      float4 w0 = *(const float4*)&W0[s*128+k0];
      float4 w1 = *(const float4*)&W1[s*128+k0];
      a0[0]+=x0v*w0.x; a0[1]+=x0v*w0.y; a0[2]+=x0v*w0.z; a0[3]+=x0v*w0.w;
      a1[0]+=x1v*w1.x; a1[1]+=x1v*w1.y; a1[2]+=x1v*w1.z; a1[3]+=x1v*w1.w;
    }
    *(float4*)&gh[(size_t)(n0+q0)*KCH + k0] = make_float4(a0[0],a0[1],a0[2],a0[3]);
    *(float4*)&gh[(size_t)(n0+q1)*KCH + k0] = make_float4(a1[0],a1[1],a1[2],a1[3]);
  }
}

// ---------------- unified polynomial contraction: fwd and/or bwd ----------------
__global__ __launch_bounds__(128) void k_poly(const float* A, const float* C1, const float* C2S, const float* P,
                                              const int* eptr, const int* eidx,
                                              float* B, float* gA,
                                              const float* gBvec, const float* gBbuf){
  __shared__ float Ps[PSZ];
  __shared__ float C2s_[256];
  __shared__ float C1s_[16];
  int t = threadIdx.x;
  int z = blockIdx.x >> 7, c = blockIdx.x & 127;
  size_t cb = (size_t)z*KCH + c;
  {
    const float4* Pg = (const float4*)(P + cb*PSZ);
    float4* Ps4 = (float4*)Ps;
    for(int i=t;i<PSZ/4;i+=128) Ps4[i] = Pg[i];
    const float4* Cg = (const float4*)(C2S + cb*256);
    float4* Cs4 = (float4*)C2s_;
    if(t<64) Cs4[t] = Cg[t];
    if(t<16) C1s_[t] = C1[cb*16 + t];
  }
  __syncthreads();
  int s0 = eptr[z], cnt = eptr[z+1]-s0;
  int half = (cnt+1)>>1;
  for(int idx=t; idx<half; idx+=128){
    int n0 = eidx[s0+idx];
    bool has1 = (idx+half < cnt);
    int n1 = has1 ? eidx[s0+idx+half] : n0;
    float a0[16], a1[16], G0[16], G1[16];
    {
      const float4* ap = (const float4*)(A + (size_t)n0*2048 + c*16);
      float4 v;
      v=ap[0]; a0[0]=v.x;a0[1]=v.y;a0[2]=v.z;a0[3]=v.w;
      v=ap[1]; a0[4]=v.x;a0[5]=v.y;a0[6]=v.z;a0[7]=v.w;
      v=ap[2]; a0[8]=v.x;a0[9]=v.y;a0[10]=v.z;a0[11]=v.w;
      v=ap[3]; a0[12]=v.x;a0[13]=v.y;a0[14]=v.z;a0[15]=v.w;
      const float4* bp = (const float4*)(A + (size_t)n1*2048 + c*16);
      v=bp[0]; a1[0]=v.x;a1[1]=v.y;a1[2]=v.z;a1[3]=v.w;
      v=bp[1]; a1[4]=v.x;a1[5]=v.y;a1[6]=v.z;a1[7]=v.w;
      v=bp[2]; a1[8]=v.x;a1[9]=v.y;a1[10]=v.z;a1[11]=v.w;
      v=bp[3]; a1[12]=v.x;a1[13]=v.y;a1[14]=v.z;a1[15]=v.w;
    }
    float b1_0=0.f, b1_1=0.f, b2_0=0.f, b2_1=0.f;
    #pragma unroll
    for(int x=0;x<16;++x){
      float cv0=0.f, cv1=0.f;
      #pragma unroll
      for(int b=0;b<16;++b){
        float wv = C2s_[x*16+b];
        cv0 += a0[b]*wv; cv1 += a1[b]*wv;
      }
      float c1v = C1s_[x];
      G0[x] = c1v + cv0;  G1[x] = c1v + cv1;
      b1_0 += a0[x]*c1v;  b1_1 += a1[x]*c1v;
      b2_0 += a0[x]*cv0;  b2_1 += a1[x]*cv1;
    }
    int pair=0;
    #pragma unroll
    for(int j=0;j<16;++j){
      #pragma unroll
      for(int k=j;k<16;++k){
        float pp0 = a0[j]*a0[k];
        float pp1 = a1[j]*a1[k];
        const float4* Pp = (const float4*)&Ps[pair*16];
        #pragma unroll
        for(int q4=0;q4<4;++q4){
          float4 pv = Pp[q4];
          G0[q4*4+0] += pp0*pv.x; G0[q4*4+1] += pp0*pv.y; G0[q4*4+2] += pp0*pv.z; G0[q4*4+3] += pp0*pv.w;
          G1[q4*4+0] += pp1*pv.x; G1[q4*4+1] += pp1*pv.y; G1[q4*4+2] += pp1*pv.z; G1[q4*4+3] += pp1*pv.w;
        }
        ++pair;
      }
    }
    if(B){
      float d0=0.f, d1=0.f;
      #pragma unroll
      for(int x=0;x<16;++x){ d0 += a0[x]*G0[x]; d1 += a1[x]*G1[x]; }
      B[(size_t)n0*KCH + c] = (2.f/3.f)*b1_0 + (1.f/6.f)*b2_0 + (1.f/3.f)*d0;
      if(has1)
        B[(size_t)n1*KCH + c] = (2.f/3.f)*b1_1 + (1.f/6.f)*b2_1 + (1.f/3.f)*d1;
    }
    if(gA){
      float g0 = gBvec ? gBvec[c] : gBbuf[(size_t)n0*KCH + c];
      float* gp0 = gA + (size_t)n0*2048 + c*16;
      #pragma unroll
      for(int x=0;x<16;++x) gp0[x] = g0*G0[x];
      if(has1){
        float g1 = gBvec ? gBvec[c] : gBbuf[(size_t)n1*KCH + c];
        float* gp1 = gA + (size_t)n1*2048 + c*16;
        #pragma unroll
        for(int x=0;x<16;++x) gp1[x] = g1*G1[x];
      }
    }
  }
}

// ---------------- fused edge backward (loads for both reps hoisted) ----------------
__global__ __launch_bounds__(256) void k_edge_bwd2(const float* gagg, const float* hup, const float* w,
                                                   const float* Y, const float* dY,
                                                   const float* vec, const float* rr,
                                                   const float* ef, const float* defdr,
                                                   const float* Wr1, const float* Wr2,
                                                   const float* Wr2T, const float* Wr3T,
                                                   const int* snds, const int* rcvs, int E,
                                                   float* ghup, float* gvec, int do_ghup, int accv){
  __shared__ float Ys[4][16];
  __shared__ float gwS[4][512];
  __shared__ float gYp[4][2][16];
  __shared__ float t1s[4][64];
  __shared__ float gz2s[4][64];
  __shared__ float efS[4][8];
  __shared__ float defS[4][8];
  int t = threadIdx.x;
  int e0 = blockIdx.x*4;
  const float inv16 = 1.f/16.f;
  if(t<64){ int le=t>>4; int ec = e0+le; if(ec<E) Ys[le][t&15] = Y[(size_t)ec*16 + (t&15)]; }
  else if(t<96){ int i=t-64; int le=i>>3; int ec=e0+le; if(ec<E) efS[le][i&7]=ef[(size_t)ec*8+(i&7)]; }
  else if(t<128){ int i=t-96; int le=i>>3; int ec=e0+le; if(ec<E) defS[le][i&7]=defdr[(size_t)ec*8+(i&7)]; }
  __syncthreads();
  {
    int k = t&127;
    int leA = t>>7, leB = leA+2;
    int eA = e0+leA, eB = e0+leB;
    bool vA = (eA<E), vB = (eB<E);
    int eCA = vA ? eA : (E-1);
    int eCB = vB ? eB : (E-1);
    int sndA = snds[eCA], rcvA = rcvs[eCA];
    int sndB = snds[eCB], rcvB = rcvs[eCB];
    // issue ALL global loads for both edges before any compute
    float hvA = hup[(size_t)sndA*KCH + k];
    float hvB = hup[(size_t)sndB*KCH + k];
    float4 w4A = ((const float4*)(w + (size_t)eCA*512))[k];
    float4 w4B = ((const float4*)(w + (size_t)eCB*512))[k];
    float ga[16], gb[16];
    {
      const float4* gpA = (const float4*)(gagg + (size_t)rcvA*2048 + k*16);
      const float4* gpB = (const float4*)(gagg + (size_t)rcvB*2048 + k*16);
      float4 v0A=gpA[0], v1A=gpA[1], v2A=gpA[2], v3A=gpA[3];
      float4 v0B=gpB[0], v1B=gpB[1], v2B=gpB[2], v3B=gpB[3];
      ga[0]=v0A.x;ga[1]=v0A.y;ga[2]=v0A.z;ga[3]=v0A.w;
      ga[4]=v1A.x;ga[5]=v1A.y;ga[6]=v1A.z;ga[7]=v1A.w;
      ga[8]=v2A.x;ga[9]=v2A.y;ga[10]=v2A.z;ga[11]=v2A.w;
      ga[12]=v3A.x;ga[13]=v3A.y;ga[14]=v3A.z;ga[15]=v3A.w;
      gb[0]=v0B.x;gb[1]=v0B.y;gb[2]=v0B.z;gb[3]=v0B.w;
      gb[4]=v1B.x;gb[5]=v1B.y;gb[6]=v1B.z;gb[7]=v1B.w;
      gb[8]=v2B.x;gb[9]=v2B.y;gb[10]=v2B.z;gb[11]=v2B.w;
      gb[12]=v3B.x;gb[13]=v3B.y;gb[14]=v3B.z;gb[15]=v3B.w;
    }
    int wv2 = (t>>6)&1;
    // ---- edge A ----
    {
      const float* Yl = Ys[leA];
      float p0 = ga[0]*Yl[0];
      float p1 = ga[1]*Yl[1]+ga[2]*Yl[2]+ga[3]*Yl[3];
      float p2 = ga[4]*Yl[4]+ga[5]*Yl[5]+ga[6]*Yl[6]+ga[7]*Yl[7]+ga[8]*Yl[8];
      float p3 = ga[9]*Yl[9]+ga[10]*Yl[10]+ga[11]*Yl[11]+ga[12]*Yl[12]+ga[13]*Yl[13]+ga[14]*Yl[14]+ga[15]*Yl[15];
      float hs = hvA*inv16;
      ((float4*)(&gwS[leA][k*4]))[0] = make_float4(p0*hs, p1*hs, p2*hs, p3*hs);
      if(do_ghup && vA){
        float s = (p0*w4A.x + p1*w4A.y + p2*w4A.z + p3*w4A.w)*inv16;
        atomicAdd(&ghup[(size_t)sndA*KCH+k], s);
      }
      float q[16];
      q[0]=ga[0]*w4A.x*hvA;
      q[1]=ga[1]*w4A.y*hvA; q[2]=ga[2]*w4A.y*hvA; q[3]=ga[3]*w4A.y*hvA;
      q[4]=ga[4]*w4A.z*hvA; q[5]=ga[5]*w4A.z*hvA; q[6]=ga[6]*w4A.z*hvA; q[7]=ga[7]*w4A.z*hvA; q[8]=ga[8]*w4A.z*hvA;
      #pragma unroll
      for(int m=9;m<16;++m) q[m]=ga[m]*w4A.w*hvA;
      #pragma unroll
      for(int m=0;m<16;++m){
        float vv=q[m];
        #pragma unroll
        for(int off2=1; off2<64; off2<<=1) vv += __shfl_xor(vv, off2, 64);
        q[m]=vv;
      }
      if((t&63)==0){
        #pragma unroll
        for(int m=0;m<16;++m) gYp[leA][wv2][m]=q[m];
      }
    }
    // ---- edge B ----
    {
      const float* Yl = Ys[leB];
      float p0 = gb[0]*Yl[0];
      float p1 = gb[1]*Yl[1]+gb[2]*Yl[2]+gb[3]*Yl[3];
      float p2 = gb[4]*Yl[4]+gb[5]*Yl[5]+gb[6]*Yl[6]+gb[7]*Yl[7]+gb[8]*Yl[8];
      float p3 = gb[9]*Yl[9]+gb[10]*Yl[10]+gb[11]*Yl[11]+gb[12]*Yl[12]+gb[13]*Yl[13]+gb[14]*Yl[14]+gb[15]*Yl[15];
      float hs = hvB*inv16;
      ((float4*)(&gwS[leB][k*4]))[0] = make_float4(p0*hs, p1*hs, p2*hs, p3*hs);
      if(do_ghup && vB){
        float s = (p0*w4B.x + p1*w4B.y + p2*w4B.z + p3*w4B.w)*inv16;
        atomicAdd(&ghup[(size_t)sndB*KCH+k], s);
      }
      float q[16];
      q[0]=gb[0]*w4B.x*hvB;
      q[1]=gb[1]*w4B.y*hvB; q[2]=gb[2]*w4B.y*hvB; q[3]=gb[3]*w4B.y*hvB;
      q[4]=gb[4]*w4B.z*hvB; q[5]=gb[5]*w4B.z*hvB; q[6]=gb[6]*w4B.z*hvB; q[7]=gb[7]*w4B.z*hvB; q[8]=gb[8]*w4B.z*hvB;
      #pragma unroll
      for(int m=9;m<16;++m) q[m]=gb[m]*w4B.w*hvB;
      #pragma unroll
      for(int m=0;m<16;++m){
        float vv=q[m];
        #pragma unroll
        for(int off2=1; off2<64; off2<<=1) vv += __shfl_xor(vv, off2, 64);
        q[m]=vv;
      }
      if((t&63)==0){
        #pragma unroll
        for(int m=0;m<16;++m) gYp[leB][wv2][m]=q[m];
      }
    }
  }
  __syncthreads();
  {
    int el = t>>6, j = t&63;
    int e = e0+el;
    bool valid = (e<E);
    int eC = valid ? e : (E-1);
    float z1=0;
    #pragma unroll
    for(int b=0;b<8;++b) z1 += efS[el][b]*Wr1[b*64+j];
    float ds1v = dsiluf(z1);
    t1s[el][j] = siluf(z1);
    __syncthreads();
    float z2=0;
    for(int i=0;i<64;++i) z2 += t1s[el][i]*Wr2[i*64+j];
    float ds2v = dsiluf(z2);
    float gt2=0;
    for(int i=0;i<512;++i) gt2 += gwS[el][i]*Wr3T[i*64+j];
    gz2s[el][j] = gt2*ds2v;
    __syncthreads();
    float gz1=0;
    for(int o=0;o<64;++o) gz1 += gz2s[el][o]*Wr2T[o*64+j];
    gz1 *= ds1v;
    float cj=0;
    #pragma unroll
    for(int b=0;b<8;++b) cj += Wr1[b*64+j]*defS[el][b];
    float p = gz1*cj;
    #pragma unroll
    for(int off2=1;off2<64;off2<<=1) p += __shfl_xor(p,off2,64);
    if(j<3 && valid){
      float s = p * vec[(size_t)eC*3+j] / rr[eC];
      #pragma unroll
      for(int m=0;m<16;++m)
        s += (gYp[el][0][m]+gYp[el][1][m])*inv16 * dY[(size_t)eC*48 + m*3 + j];
      if(accv) gvec[(size_t)eC*3+j] += s;
      else     gvec[(size_t)eC*3+j]  = s;
    }
  }
}

// ---------------- energy readout ----------------
__global__ void k_energy(const float* h2, const float* Wro, const float* AE,
                         const int* elem, const int* batch, float* out, int N){
  int n = blockIdx.x*256 + threadIdx.x;
  if(n>=N) return;
  float s=0;
  for(int k=0;k<KCH;++k) s += h2[(size_t)n*KCH+k]*Wro[k];
  s += AE[elem[n]];
  atomicAdd(&out[batch[n]], s);
}

// ---------------- forces scatter ----------------
__global__ void k_forces(const float* gvec, const int* snds, const int* rcvs, int E, float* fout){
  int i = blockIdx.x*256 + threadIdx.x;
  if(i>=E*3) return;
  int e = i/3, j = i - e*3;
  float g = gvec[i];
  atomicAdd(&fout[(size_t)snds[e]*3+j], g);
  atomicAdd(&fout[(size_t)rcvs[e]*3+j], -g);
}

// =============================================================
extern "C" void kernel_launch(void* const* d_in, const int* in_sizes, int n_in,
                              void* d_out, int out_size, void* d_ws, size_t ws_size,
                              hipStream_t stream){
  const float* attrs  = (const float*)d_in[0];
  const float* pos    = (const float*)d_in[1];
  const float* shifts = (const float*)d_in[2];
  const float* AE     = (const float*)d_in[3];
  const float* Wemb   = (const float*)d_in[4];
  const float* Wup    = (const float*)d_in[5];
  const float* Wr1    = (const float*)d_in[6];
  const float* Wr2    = (const float*)d_in[7];
  const float* Wr3    = (const float*)d_in[8];
  const float* Wlin   = (const float*)d_in[9];
  const float* Wskip  = (const float*)d_in[10];
  const float* U1     = (const float*)d_in[11];
  const float* U2     = (const float*)d_in[12];
  const float* U3     = (const float*)d_in[13];
  const float* Wc1    = (const float*)d_in[14];
  const float* Wc2    = (const float*)d_in[15];
  const float* Wc3    = (const float*)d_in[16];
  const float* Wprod  = (const float*)d_in[17];
  const float* Wro    = (const float*)d_in[18];
  const int*   ei     = (const int*)d_in[19];
  const int*   batch  = (const int*)d_in[20];
  int N = in_sizes[1]/3;
  int E = in_sizes[19]/2;
  float* out = (float*)d_out;
  int G = out_size - 3*N;

  char* base = (char*)d_ws;
  size_t off = 0;
  auto alloc = [&](size_t nbytes)->void*{
    void* p = base + off;
    off += (nbytes + 255) & ~(size_t)255;
    return p;
  };
  int* elem = (int*)alloc((size_t)N*4);
  int* rptr = (int*)alloc((size_t)(N+1)*4);
  // zeroed counter block (contiguous)
  int* rcnt = (int*)alloc((size_t)N*4);
  int* rcur = (int*)alloc((size_t)N*4);
  int* ecnt = (int*)alloc((size_t)NELEM*4);
  int* ecur = (int*)alloc((size_t)NELEM*4);
  size_t zspan = (size_t)((base+off) - (char*)rcnt) / 4;
  int* ridx = (int*)alloc((size_t)E*4);
  int* eptr = (int*)alloc((size_t)(NELEM+1)*4);
  int* eidx = (int*)alloc((size_t)N*4);
  int* snds = (int*)alloc((size_t)E*4);
  int* rcvs = (int*)alloc((size_t)E*4);
  float* h0   = (float*)alloc((size_t)N*KCH*4);
  float* h1   = (float*)alloc((size_t)N*KCH*4);
  float* h2   = (float*)alloc((size_t)N*KCH*4);
  float* hup0 = (float*)alloc((size_t)N*KCH*4);
  float* hup1 = (float*)alloc((size_t)N*KCH*4);
  float* vecb = (float*)alloc((size_t)E*3*4);
  float* rb   = (float*)alloc((size_t)E*4);
  float* Yb   = (float*)alloc((size_t)E*16*4);
  float* dYb  = (float*)alloc((size_t)E*48*4);
  float* efb  = (float*)alloc((size_t)E*8*4);
  float* defb = (float*)alloc((size_t)E*8*4);
  float* wb   = (float*)alloc((size_t)E*512*4);
  float* A0   = (float*)alloc((size_t)N*2048*4);
  float* A1   = (float*)alloc((size_t)N*2048*4);
  float* aggb = (float*)alloc((size_t)N*2048*4);
  float* gAb  = (float*)alloc((size_t)N*2048*4);
  float* Bbuf = (float*)alloc((size_t)N*KCH*4);
  float* gh1  = (float*)alloc((size_t)N*KCH*4);
  float* ghup = (float*)alloc((size_t)N*KCH*4);
  float* gB0b = (float*)alloc((size_t)N*KCH*4);
  float* gB1v = (float*)alloc((size_t)KCH*4);
  float* gvecb= (float*)alloc((size_t)E*3*4);
  float* C1b  = (float*)alloc((size_t)NELEM*KCH*16*4);
  float* C2Sb = (float*)alloc((size_t)NELEM*KCH*256*4);
  float* Pb   = (float*)alloc((size_t)NELEM*KCH*PSZ*4);
  float* U2s  = (float*)alloc(1024*4);
  float* U3s  = (float*)alloc(32768*4);
  float* WupT1   = (float*)alloc(16384*4);
  float* WprodT0 = (float*)alloc(16384*4);
  float* WskipT1 = (float*)alloc((size_t)NELEM*16384*4);
  float* Wbig0  = (float*)alloc((size_t)16*16384*4);
  float* Wbig1  = (float*)alloc((size_t)16*16384*4);
  float* WbigT0 = (float*)alloc((size_t)16*16384*4);
  float* WbigT1 = (float*)alloc((size_t)16*16384*4);
  float* Wr3T0   = (float*)alloc(32768*4);
  float* Wr3T1   = (float*)alloc(32768*4);
  float* Wr2T0   = (float*)alloc(4096*4);
  float* Wr2T1   = (float*)alloc(4096*4);
  if(off > ws_size) return; // insufficient workspace

  // PRIORITY 1: second C-tensor set (layer-1) — enables fused layer-1 fwd+bwd poly
  float *C1_1=C1b, *C2_1=C2Sb, *P_1=Pb; int have_c2 = 0;
  {
    size_t need = ((size_t)NELEM*KCH*16 + (size_t)NELEM*KCH*256 + (size_t)NELEM*KCH*PSZ)*4 + 1024;
    if(off + need <= ws_size){
      C1_1 = (float*)alloc((size_t)NELEM*KCH*16*4);
      C2_1 = (float*)alloc((size_t)NELEM*KCH*256*4);
      P_1  = (float*)alloc((size_t)NELEM*KCH*PSZ*4);
      have_c2 = 1;
    }
  }
  // PRIORITY 2: second w buffer (layer-1 w)
  float* wb1 = wb; int have_wb1 = 0;
  if(off + (size_t)E*512*4 <= ws_size){ wb1 = (float*)alloc((size_t)E*512*4); have_wb1 = 1; }

  const int KK = KCH*KCH;           // 16384
  dim3 b256(256), b128(128);
  #define GR(n) dim3(((n)+255)/256)

  // zeros (counters fused; out; ghup)
  k_zero<<<GR(out_size),b256,0,stream>>>(out, out_size);
  k_zero<<<GR((int)zspan),b256,0,stream>>>((float*)rcnt, (int)zspan);
  k_zero<<<GR(N*KCH),b256,0,stream>>>(ghup, N*KCH);

  // elem + embed
  k_elem<<<GR(N),b256,0,stream>>>(attrs, elem, N);
  k_h0<<<GR(N*KCH),b256,0,stream>>>(Wemb, elem, h0, N);

  // CSR by recv
  k_hist<<<GR(E),b256,0,stream>>>(ei+E, rcnt, E);
  k_scan<<<1,b256,0,stream>>>(rcnt, rptr, N);
  k_scatter<<<GR(E),b256,0,stream>>>(ei+E, rptr, rcur, ridx, E);
  // node lists by element
  k_hist<<<GR(N),b256,0,stream>>>(elem, ecnt, N);
  k_scan<<<1,b256,0,stream>>>(ecnt, eptr, NELEM);
  k_scatter<<<GR(N),b256,0,stream>>>(elem, eptr, ecur, eidx, N);

  // fused weight prep
  k_prep<<<GR(PREP_ITEMS),b256,0,stream>>>(Wup, Wprod, Wskip, Wlin, Wr2, Wr3, U2, U3,
                                           WupT1, WprodT0, WskipT1,
                                           Wbig0, Wbig1, WbigT0, WbigT1,
                                           Wr3T0, Wr3T1, Wr2T0, Wr2T1, U2s, U3s);
  k_gB1<<<1,b128,0,stream>>>(Wro, Wprod + KK, gB1v);

  // edge geometry (sorted order)
  k_edge_geom<<<GR(E),b256,0,stream>>>(pos, shifts, ei, ridx, E, snds, rcvs,
                                       vecb, rb, Yb, dYb, efb, defb);

  dim3 mmG((N+7)/8);
  dim3 mxG((N+3)/4);
  dim3 polyG(NELEM*KCH);
  dim3 rwG((E+15)/16);
  dim3 ebG((E+3)/4);

  // ---------- layer 0 forward ----------
  k_ctens<<<GR(CTENS_ITEMS),b256,0,stream>>>(U1, U2s, U3s, Wc1, Wc2, Wc3, C1b, C2Sb, Pb);
  k_mm<<<mmG,b128,0,stream>>>(h0, Wup, hup0, N, 0);
  k_radial_w<<<rwG,b256,0,stream>>>(efb, Wr1, Wr2, Wr3, wb, E);
  k_gather<<<dim3(N),b256,0,stream>>>(hup0, wb, Yb, rptr, snds, aggb, E);
  k_mixed2<<<mxG,b256,0,stream>>>(aggb, h0, elem, Wbig0, Wskip, A0, nullptr, N, 0);
  k_poly<<<polyG,b128,0,stream>>>(A0, C1b, C2Sb, Pb, eptr, eidx, Bbuf, nullptr, nullptr, nullptr);
  k_mm<<<mmG,b128,0,stream>>>(Bbuf, Wprod, h1, N, 0);

  // ---------- layer 1 forward (poly also emits gA1 since gB1 is data-independent) ----------
  k_ctens<<<GR(CTENS_ITEMS),b256,0,stream>>>(U1, U2s, U3s,
                                             Wc1 + NELEM*2*KCH, Wc2 + NELEM*4*KCH, Wc3 + NELEM*8*KCH,
                                             C1_1, C2_1, P_1);
  k_mm<<<mmG,b128,0,stream>>>(h1, Wup + KK, hup1, N, 0);
  k_radial_w<<<rwG,b256,0,stream>>>(efb, Wr1 + 512, Wr2 + 4096, Wr3 + 32768, wb1, E);
  k_gather<<<dim3(N),b256,0,stream>>>(hup1, wb1, Yb, rptr, snds, aggb, E);
  k_mixed2<<<mxG,b256,0,stream>>>(aggb, h1, elem, Wbig1, Wskip + (size_t)NELEM*KK, A1, nullptr, N, 0);
  k_poly<<<polyG,b128,0,stream>>>(A1, C1_1, C2_1, P_1, eptr, eidx, Bbuf, gAb, gB1v, nullptr);
  k_mm<<<mmG,b128,0,stream>>>(Bbuf, Wprod + KK, h2, N, 0);

  // energy
  k_energy<<<GR(N),b256,0,stream>>>(h2, Wro, AE, elem, batch, out, N);

  // ---------- layer 1 backward (gAb already computed) ----------
  k_mixed2<<<mxG,b256,0,stream>>>(gAb, nullptr, elem, WbigT1, WskipT1, aggb, gh1, N, 2);
  k_edge_bwd2<<<ebG,b256,0,stream>>>(aggb, hup1, wb1, Yb, dYb, vecb, rb, efb, defb,
                                     Wr1 + 512, Wr2 + 4096, Wr2T1, Wr3T1, snds, rcvs, E,
                                     ghup, gvecb, 1, 0);
  k_mm<<<mmG,b128,0,stream>>>(ghup, WupT1, gh1, N, 1);

  // ---------- layer 0 backward ----------
  if(!have_c2)
    k_ctens<<<GR(CTENS_ITEMS),b256,0,stream>>>(U1, U2s, U3s, Wc1, Wc2, Wc3, C1b, C2Sb, Pb);
  k_mm<<<mmG,b128,0,stream>>>(gh1, WprodT0, gB0b, N, 0);
  k_poly<<<polyG,b128,0,stream>>>(A0, C1b, C2Sb, Pb, eptr, eidx, nullptr, gAb, nullptr, gB0b);
  k_mixed2<<<mxG,b256,0,stream>>>(gAb, nullptr, elem, WbigT0, nullptr, aggb, nullptr, N, 1);
  if(!have_wb1)
    k_radial_w<<<rwG,b256,0,stream>>>(efb, Wr1, Wr2, Wr3, wb, E);
  k_edge_bwd2<<<ebG,b256,0,stream>>>(aggb, hup0, wb, Yb, dYb, vecb, rb, efb, defb,
                                     Wr1, Wr2, Wr2T0, Wr3T0, snds, rcvs, E,
                                     ghup, gvecb, 0, 1);

  // forces
  k_forces<<<GR(E*3),b256,0,stream>>>(gvecb, snds, rcvs, E, out + G);
  #undef GR
}